// Round 1
// baseline (778.154 us; speedup 1.0000x reference)
//
#include <hip/hip_runtime.h>

typedef unsigned short ushort_t;
typedef __bf16 bf16x8 __attribute__((ext_vector_type(8)));
typedef float floatx4 __attribute__((ext_vector_type(4)));

#define B_ 8
#define N_ 8192
#define S_ 2048
#define D1_ 128
#define D2_ 256
#define INCH_ 384
#define M_ 65536  // B*N

// ---------- workspace layout (bytes) ----------
// stats floats: sum0[256] ssq0[256] sum1[128] ssq1[128] scale0[256] shift0[256] scale1[128] shift1[128]
constexpr size_t OFF_STATS = 0;          // 6144 B used
constexpr size_t OFF_W0B   = 8192;       // 256*384*2 = 196608
constexpr size_t OFF_W1B   = 204800;     // 128*256*2 = 65536
constexpr size_t OFF_X2P   = 270336;     // 8*2048*16 = 262144 (float4 x,y,z,0.5*|x|^2)
constexpr size_t OFF_P2T   = 532480;     // 8*2048*256*2 = 8388608 bf16
constexpr size_t OFF_XC    = 8921088;    // 65536*384*2 = 50331648 bf16 ; X1 overlays this later
constexpr size_t OFF_Y1    = 59252736;   // 65536*256*4 = 67108864 f32  ; Y2 overlays this later
// total ~126.4 MB

__device__ __forceinline__ ushort_t f2bf(float f) {
  unsigned int u = __float_as_uint(f);
  unsigned int r = u + 0x7fffu + ((u >> 16) & 1u);
  return (ushort_t)(r >> 16);
}
__device__ __forceinline__ float bf2f(ushort_t h) {
  return __uint_as_float(((unsigned int)h) << 16);
}

#define LESSI(da, ia, db, ib) ((da) < (db) || ((da) == (db) && (ia) < (ib)))

__device__ __forceinline__ void insert3(float d, int s,
                                        float& c0, int& i0,
                                        float& c1, int& i1,
                                        float& c2, int& i2) {
  bool l0 = LESSI(d, s, c0, i0);
  bool l1 = LESSI(d, s, c1, i1);
  bool l2 = LESSI(d, s, c2, i2);
  float n2 = l1 ? c1 : (l2 ? d : c2); int m2 = l1 ? i1 : (l2 ? s : i2);
  float n1 = l0 ? c0 : (l1 ? d : c1); int m1 = l0 ? i0 : (l1 ? s : i1);
  float n0 = l0 ? d  : c0;            int m0 = l0 ? s  : i0;
  c0 = n0; c1 = n1; c2 = n2; i0 = m0; i1 = m1; i2 = m2;
}

// ---------- weights fp32 -> bf16 ----------
__global__ __launch_bounds__(256) void k_prep_weights(const float* __restrict__ W0,
                                                      const float* __restrict__ W1,
                                                      ushort_t* __restrict__ W0b,
                                                      ushort_t* __restrict__ W1b) {
  int i = blockIdx.x * 256 + threadIdx.x;  // grid 512 -> 131072 = 98304 + 32768
  if (i < 98304) W0b[i] = f2bf(W0[i]);
  else           W1b[i - 98304] = f2bf(W1[i - 98304]);
}

// ---------- pack xyz2 -> (x,y,z,0.5*|x|^2) ----------
__global__ __launch_bounds__(256) void k_pack_xyz2(const float* __restrict__ xyz2,
                                                   float4* __restrict__ x2p) {
  int idx = blockIdx.x * 256 + threadIdx.x;  // 16384
  int b = idx >> 11, s = idx & (S_ - 1);
  const float* base = xyz2 + (size_t)b * 3 * S_;
  float x = base[s], y = base[S_ + s], z = base[2 * S_ + s];
  x2p[idx] = make_float4(x, y, z, 0.5f * (x * x + y * y + z * z));
}

// ---------- transpose points2 [B,256,S] -> p2t bf16 [B,S,256] ----------
__global__ void k_tr_p2(const float* __restrict__ P2, ushort_t* __restrict__ p2t) {
  __shared__ float t[32][33];
  int b = blockIdx.z;
  int s0 = blockIdx.x * 32;   // grid.x = 64
  int c0 = blockIdx.y * 32;   // grid.y = 8
  int tx = threadIdx.x, ty = threadIdx.y;  // (32,8)
#pragma unroll
  for (int j = 0; j < 4; j++) {
    int c = c0 + ty + j * 8;
    t[ty + j * 8][tx] = P2[((size_t)b * D2_ + c) * S_ + s0 + tx];
  }
  __syncthreads();
#pragma unroll
  for (int j = 0; j < 4; j++) {
    int s = s0 + ty + j * 8;
    p2t[((size_t)b * S_ + s) * D2_ + c0 + tx] = f2bf(t[tx][ty + j * 8]);
  }
}

// ---------- transpose points1 [B,128,N] -> Xc cols 0..127 (bf16, row stride 384) ----------
__global__ void k_tr_p1(const float* __restrict__ P1, ushort_t* __restrict__ Xc) {
  __shared__ float t[32][33];
  int b = blockIdx.z;
  int n0 = blockIdx.x * 32;   // grid.x = 256
  int c0 = blockIdx.y * 32;   // grid.y = 4
  int tx = threadIdx.x, ty = threadIdx.y;
#pragma unroll
  for (int j = 0; j < 4; j++) {
    int c = c0 + ty + j * 8;
    t[ty + j * 8][tx] = P1[((size_t)b * D1_ + c) * N_ + n0 + tx];
  }
  __syncthreads();
#pragma unroll
  for (int j = 0; j < 4; j++) {
    int n = n0 + ty + j * 8;
    Xc[((size_t)b * N_ + n) * INCH_ + c0 + tx] = f2bf(t[tx][ty + j * 8]);
  }
}

// ---------- interpolation: one block per query point ----------
__global__ __launch_bounds__(256) void k_interp(const float* __restrict__ xyz1,
                                                const float4* __restrict__ x2p,
                                                const ushort_t* __restrict__ p2t,
                                                ushort_t* __restrict__ Xc) {
  __shared__ float4 xs[S_];     // 32 KB
  __shared__ float rd[768];
  __shared__ int ri[768];
  __shared__ float wsh[3];
  __shared__ int ish[3];
  int tid = threadIdx.x;
  int p = blockIdx.x;           // 65536 blocks
  int b = p >> 13;
  int n = p & (N_ - 1);
  float qx = xyz1[((size_t)b * 3 + 0) * N_ + n];
  float qy = xyz1[((size_t)b * 3 + 1) * N_ + n];
  float qz = xyz1[((size_t)b * 3 + 2) * N_ + n];
  float nrm1 = qx * qx + qy * qy + qz * qz;
  for (int l = tid; l < S_; l += 256) xs[l] = x2p[(size_t)b * S_ + l];
  __syncthreads();
  // d = |x1|^2 - 2*dot + |x2|^2 = 2*e + |x1|^2 where e = 0.5*|x2|^2 - dot
  float c0 = 3e38f, c1 = 3e38f, c2 = 3e38f;
  int i0 = 0x7fffffff, i1 = 0x7fffffff, i2 = 0x7fffffff;
#pragma unroll
  for (int it = 0; it < 8; it++) {
    int s = tid + it * 256;
    float4 q = xs[s];
    float e = fmaf(-qx, q.x, fmaf(-qy, q.y, fmaf(-qz, q.z, q.w)));
    insert3(e, s, c0, i0, c1, i1, c2, i2);
  }
  rd[tid * 3 + 0] = c0; rd[tid * 3 + 1] = c1; rd[tid * 3 + 2] = c2;
  ri[tid * 3 + 0] = i0; ri[tid * 3 + 1] = i1; ri[tid * 3 + 2] = i2;
  __syncthreads();
  for (int off = 128; off > 0; off >>= 1) {
    if (tid < off) {
      int o = (tid + off) * 3;
      float d0 = rd[o], d1 = rd[o + 1], d2 = rd[o + 2];
      int j0 = ri[o], j1 = ri[o + 1], j2 = ri[o + 2];
      insert3(d0, j0, c0, i0, c1, i1, c2, i2);
      insert3(d1, j1, c0, i0, c1, i1, c2, i2);
      insert3(d2, j2, c0, i0, c1, i1, c2, i2);
      rd[tid * 3 + 0] = c0; rd[tid * 3 + 1] = c1; rd[tid * 3 + 2] = c2;
      ri[tid * 3 + 0] = i0; ri[tid * 3 + 1] = i1; ri[tid * 3 + 2] = i2;
    }
    __syncthreads();
  }
  if (tid == 0) {
    float dd0 = fmaf(2.f, rd[0], nrm1);
    float dd1 = fmaf(2.f, rd[1], nrm1);
    float dd2 = fmaf(2.f, rd[2], nrm1);
    float r0 = 1.f / (dd0 + 1e-8f);
    float r1 = 1.f / (dd1 + 1e-8f);
    float r2 = 1.f / (dd2 + 1e-8f);
    float rs = r0 + r1 + r2;
    wsh[0] = r0 / rs; wsh[1] = r1 / rs; wsh[2] = r2 / rs;
    ish[0] = ri[0]; ish[1] = ri[1]; ish[2] = ri[2];
  }
  __syncthreads();
  float w0 = wsh[0], w1 = wsh[1], w2 = wsh[2];
  int j0 = ish[0], j1 = ish[1], j2 = ish[2];
  int c = tid;  // 256 channels
  size_t base = (size_t)b * S_;
  float f0 = bf2f(p2t[(base + j0) * D2_ + c]);
  float f1 = bf2f(p2t[(base + j1) * D2_ + c]);
  float f2 = bf2f(p2t[(base + j2) * D2_ + c]);
  Xc[(size_t)p * INCH_ + D1_ + c] = f2bf(w0 * f0 + w1 * f1 + w2 * f2);
}

// ---------- bf16 MFMA GEMM: C[M,Nout] = A[M,K] * W[Nout,K]^T (fp32 out) ----------
__global__ __launch_bounds__(256) void k_gemm(const ushort_t* __restrict__ A,
                                              const ushort_t* __restrict__ Bw,
                                              float* __restrict__ Cc,
                                              int M, int K, int Nout) {
  __shared__ __align__(16) ushort_t As[128 * 32];
  __shared__ __align__(16) ushort_t Bs[128 * 32];
  const int tid = threadIdx.x;
  const int m0 = blockIdx.x * 128;
  const int n0 = blockIdx.y * 128;
  const int wave = tid >> 6;
  const int lane = tid & 63;
  const int quad = lane >> 4;
  const int l16 = lane & 15;
  const int wrow = (wave >> 1) * 64;
  const int wcol = (wave & 1) * 64;
  floatx4 acc[4][4];
#pragma unroll
  for (int i = 0; i < 4; i++)
#pragma unroll
    for (int j = 0; j < 4; j++) acc[i][j] = (floatx4){0.f, 0.f, 0.f, 0.f};

  for (int k0 = 0; k0 < K; k0 += 32) {
#pragma unroll
    for (int it = 0; it < 2; it++) {
      int l = tid + it * 256;
      int row = l >> 2, seg = l & 3;
      *(uint4*)&As[row * 32 + seg * 8] = *(const uint4*)&A[(size_t)(m0 + row) * K + k0 + seg * 8];
      *(uint4*)&Bs[row * 32 + seg * 8] = *(const uint4*)&Bw[(size_t)(n0 + row) * K + k0 + seg * 8];
    }
    __syncthreads();
    bf16x8 af[4], bfr[4];
#pragma unroll
    for (int mt = 0; mt < 4; mt++) af[mt] = *(const bf16x8*)&As[(wrow + mt * 16 + l16) * 32 + quad * 8];
#pragma unroll
    for (int nt = 0; nt < 4; nt++) bfr[nt] = *(const bf16x8*)&Bs[(wcol + nt * 16 + l16) * 32 + quad * 8];
#pragma unroll
    for (int mt = 0; mt < 4; mt++)
#pragma unroll
      for (int nt = 0; nt < 4; nt++)
        acc[mt][nt] = __builtin_amdgcn_mfma_f32_16x16x32_bf16(af[mt], bfr[nt], acc[mt][nt], 0, 0, 0);
    __syncthreads();
  }
#pragma unroll
  for (int mt = 0; mt < 4; mt++) {
#pragma unroll
    for (int i = 0; i < 4; i++) {
      int row = m0 + wrow + mt * 16 + quad * 4 + i;
#pragma unroll
      for (int nt = 0; nt < 4; nt++) {
        int col = n0 + wcol + nt * 16 + l16;
        Cc[(size_t)row * Nout + col] = acc[mt][nt][i];
      }
    }
  }
}

// ---------- BN stats: per-channel sum / sumsq ----------
__global__ __launch_bounds__(256) void k_stats(const float* __restrict__ Y,
                                               float* __restrict__ sum,
                                               float* __restrict__ ssq,
                                               int C, int rowsPerBlock) {
  int tid = threadIdx.x;
  int c = tid & (C - 1);
  int rsub = tid / C;
  int step = 256 / C;
  int r0 = blockIdx.x * rowsPerBlock;
  float s = 0.f, s2 = 0.f;
  for (int r = rsub; r < rowsPerBlock; r += step) {
    float v = Y[(size_t)(r0 + r) * C + c];
    s += v;
    s2 += v * v;
  }
  atomicAdd(&sum[c], s);
  atomicAdd(&ssq[c], s2);
}

__global__ void k_finalize(const float* __restrict__ sum, const float* __restrict__ ssq,
                           const float* __restrict__ g, const float* __restrict__ be,
                           float* __restrict__ scale, float* __restrict__ shift,
                           float inv_count) {
  int c = threadIdx.x;
  float mean = sum[c] * inv_count;
  float var = ssq[c] * inv_count - mean * mean;
  float sc = rsqrtf(var + 1e-5f) * g[c];
  scale[c] = sc;
  shift[c] = be[c] - mean * sc;
}

// ---------- normalize + relu -> bf16 (layer 1 activations) ----------
__global__ __launch_bounds__(256) void k_norm_relu(const float4* __restrict__ Y,
                                                   const float* __restrict__ scale,
                                                   const float* __restrict__ shift,
                                                   ushort_t* __restrict__ X) {
  int idx = blockIdx.x * 256 + threadIdx.x;  // 4194304 float4s
  float4 y = Y[idx];
  int c = (idx & 63) * 4;  // 256 channels / 4 per float4
  float v0 = fmaxf(fmaf(y.x, scale[c + 0], shift[c + 0]), 0.f);
  float v1 = fmaxf(fmaf(y.y, scale[c + 1], shift[c + 1]), 0.f);
  float v2 = fmaxf(fmaf(y.z, scale[c + 2], shift[c + 2]), 0.f);
  float v3 = fmaxf(fmaf(y.w, scale[c + 3], shift[c + 3]), 0.f);
  ushort4 o;
  o.x = f2bf(v0); o.y = f2bf(v1); o.z = f2bf(v2); o.w = f2bf(v3);
  *(ushort4*)&X[(size_t)idx * 4] = o;
}

// ---------- final: BN + relu + transpose to [B,128,N] ----------
__global__ __launch_bounds__(256) void k_out(const float* __restrict__ Y2,
                                             const float* __restrict__ scale,
                                             const float* __restrict__ shift,
                                             float* __restrict__ out) {
  __shared__ float t[64 * 129];  // 33 KB
  int tid = threadIdx.x;
  int p0 = blockIdx.x * 64;  // 1024 blocks
  int b = p0 >> 13;
  int n0 = p0 & (N_ - 1);
#pragma unroll
  for (int it = 0; it < 32; it++) {
    int idx = it * 256 + tid;
    int r = idx >> 7, c = idx & 127;
    t[r * 129 + c] = Y2[(size_t)(p0 + r) * 128 + c];
  }
  __syncthreads();
#pragma unroll
  for (int it = 0; it < 32; it++) {
    int idx = it * 256 + tid;
    int j = idx & 63, c = idx >> 6;
    float v = fmaxf(fmaf(t[j * 129 + c], scale[c], shift[c]), 0.f);
    out[((size_t)(b * 128 + c)) * N_ + n0 + j] = v;
  }
}

extern "C" void kernel_launch(void* const* d_in, const int* in_sizes, int n_in,
                              void* d_out, int out_size, void* d_ws, size_t ws_size,
                              hipStream_t stream) {
  const float* xyz1    = (const float*)d_in[0];
  const float* xyz2    = (const float*)d_in[1];
  const float* points1 = (const float*)d_in[2];
  const float* points2 = (const float*)d_in[3];
  const float* W0 = (const float*)d_in[4];
  const float* g0 = (const float*)d_in[6];
  const float* be0 = (const float*)d_in[7];
  const float* W1 = (const float*)d_in[8];
  const float* g1 = (const float*)d_in[10];
  const float* be1 = (const float*)d_in[11];
  float* out = (float*)d_out;
  char* ws = (char*)d_ws;

  float* sum0   = (float*)(ws + OFF_STATS);
  float* ssq0   = sum0 + 256;
  float* sum1   = sum0 + 512;
  float* ssq1   = sum0 + 640;
  float* scale0 = sum0 + 768;
  float* shift0 = sum0 + 1024;
  float* scale1 = sum0 + 1280;
  float* shift1 = sum0 + 1408;
  ushort_t* W0b = (ushort_t*)(ws + OFF_W0B);
  ushort_t* W1b = (ushort_t*)(ws + OFF_W1B);
  float4* x2p   = (float4*)(ws + OFF_X2P);
  ushort_t* p2t = (ushort_t*)(ws + OFF_P2T);
  ushort_t* Xc  = (ushort_t*)(ws + OFF_XC);
  ushort_t* X1  = (ushort_t*)(ws + OFF_XC);   // overlays Xc (dead after GEMM1)
  float* Y1     = (float*)(ws + OFF_Y1);
  float* Y2     = (float*)(ws + OFF_Y1);       // overlays Y1 (dead after norm)

  hipMemsetAsync(ws + OFF_STATS, 0, 6144, stream);
  k_prep_weights<<<512, 256, 0, stream>>>(W0, W1, W0b, W1b);
  k_pack_xyz2<<<64, 256, 0, stream>>>(xyz2, x2p);
  k_tr_p2<<<dim3(64, 8, 8), dim3(32, 8), 0, stream>>>(points2, p2t);
  k_tr_p1<<<dim3(256, 4, 8), dim3(32, 8), 0, stream>>>(points1, Xc);
  k_interp<<<M_, 256, 0, stream>>>(xyz1, x2p, p2t, Xc);
  k_gemm<<<dim3(512, 2), 256, 0, stream>>>(Xc, W0b, Y1, M_, 384, 256);
  k_stats<<<256, 256, 0, stream>>>(Y1, sum0, ssq0, 256, 256);
  k_finalize<<<1, 256, 0, stream>>>(sum0, ssq0, g0, be0, scale0, shift0, 1.f / 65536.f);
  k_norm_relu<<<16384, 256, 0, stream>>>((const float4*)Y1, scale0, shift0, X1);
  k_gemm<<<dim3(512, 1), 256, 0, stream>>>(X1, W1b, Y2, M_, 256, 128);
  k_stats<<<256, 256, 0, stream>>>(Y2, sum1, ssq1, 128, 256);
  k_finalize<<<1, 128, 0, stream>>>(sum1, ssq1, g1, be1, scale1, shift1, 1.f / 65536.f);
  k_out<<<1024, 256, 0, stream>>>(Y2, scale1, shift1, out);
}

// Round 2
// 408.580 us; speedup vs baseline: 1.9045x; 1.9045x over previous
//
#include <hip/hip_runtime.h>

typedef unsigned short ushort_t;
typedef __bf16 bf16x8 __attribute__((ext_vector_type(8)));
typedef float floatx4 __attribute__((ext_vector_type(4)));

#define B_ 8
#define N_ 8192
#define S_ 2048
#define D1_ 128
#define D2_ 256
#define INCH_ 384
#define M_ 65536  // B*N

// ---------- workspace layout (bytes) ----------
constexpr size_t OFF_STATS = 0;          // 6144 B used
constexpr size_t OFF_W0B   = 8192;       // 256*384*2 = 196608
constexpr size_t OFF_W1B   = 204800;     // 128*256*2 = 65536
constexpr size_t OFF_X2P   = 270336;     // 8*2048*16 = 262144 (float4 x,y,z,0.5*|x|^2)
constexpr size_t OFF_P2T   = 532480;     // 8*2048*256*2 = 8388608 bf16
constexpr size_t OFF_XC    = 8921088;    // 65536*384*2 = 50331648 bf16 ; X1 overlays this later
constexpr size_t OFF_Y1    = 59252736;   // 65536*256*4 = 67108864 f32  ; Y2 overlays this later
// total ~126.4 MB (same as round-1 layout which fit)

__device__ __forceinline__ ushort_t f2bf(float f) {
  unsigned int u = __float_as_uint(f);
  unsigned int r = u + 0x7fffu + ((u >> 16) & 1u);
  return (ushort_t)(r >> 16);
}
__device__ __forceinline__ float bf2f(ushort_t h) {
  return __uint_as_float(((unsigned int)h) << 16);
}

// ---------- weights fp32 -> bf16 ----------
__global__ __launch_bounds__(256) void k_prep_weights(const float* __restrict__ W0,
                                                      const float* __restrict__ W1,
                                                      ushort_t* __restrict__ W0b,
                                                      ushort_t* __restrict__ W1b) {
  int i = blockIdx.x * 256 + threadIdx.x;  // grid 512 -> 131072 = 98304 + 32768
  if (i < 98304) W0b[i] = f2bf(W0[i]);
  else           W1b[i - 98304] = f2bf(W1[i - 98304]);
}

// ---------- pack xyz2 -> (x,y,z,0.5*|x|^2) ----------
__global__ __launch_bounds__(256) void k_pack_xyz2(const float* __restrict__ xyz2,
                                                   float4* __restrict__ x2p) {
  int idx = blockIdx.x * 256 + threadIdx.x;  // 16384
  int b = idx >> 11, s = idx & (S_ - 1);
  const float* base = xyz2 + (size_t)b * 3 * S_;
  float x = base[s], y = base[S_ + s], z = base[2 * S_ + s];
  x2p[idx] = make_float4(x, y, z, 0.5f * (x * x + y * y + z * z));
}

// ---------- transpose points2 [B,256,S] -> p2t bf16 [B,S,256] ----------
__global__ void k_tr_p2(const float* __restrict__ P2, ushort_t* __restrict__ p2t) {
  __shared__ float t[32][33];
  int b = blockIdx.z;
  int s0 = blockIdx.x * 32;   // grid.x = 64
  int c0 = blockIdx.y * 32;   // grid.y = 8
  int tx = threadIdx.x, ty = threadIdx.y;  // (32,8)
#pragma unroll
  for (int j = 0; j < 4; j++) {
    int c = c0 + ty + j * 8;
    t[ty + j * 8][tx] = P2[((size_t)b * D2_ + c) * S_ + s0 + tx];
  }
  __syncthreads();
#pragma unroll
  for (int j = 0; j < 4; j++) {
    int s = s0 + ty + j * 8;
    p2t[((size_t)b * S_ + s) * D2_ + c0 + tx] = f2bf(t[tx][ty + j * 8]);
  }
}

// ---------- transpose points1 [B,128,N] -> Xc cols 0..127 (bf16, row stride 384) ----------
__global__ void k_tr_p1(const float* __restrict__ P1, ushort_t* __restrict__ Xc) {
  __shared__ float t[32][33];
  int b = blockIdx.z;
  int n0 = blockIdx.x * 32;   // grid.x = 256
  int c0 = blockIdx.y * 32;   // grid.y = 4
  int tx = threadIdx.x, ty = threadIdx.y;
#pragma unroll
  for (int j = 0; j < 4; j++) {
    int c = c0 + ty + j * 8;
    t[ty + j * 8][tx] = P1[((size_t)b * D1_ + c) * N_ + n0 + tx];
  }
  __syncthreads();
#pragma unroll
  for (int j = 0; j < 4; j++) {
    int n = n0 + ty + j * 8;
    Xc[((size_t)b * N_ + n) * INCH_ + c0 + tx] = f2bf(t[tx][ty + j * 8]);
  }
}

// ---------- kNN + interpolate: 512 blocks, 128 queries/block ----------
// thread t: sub = t>>5 (S-chunk of 256 points), qg = t&31 (4 queries)
__global__ __launch_bounds__(256) void k_knn(const float* __restrict__ xyz1,
                                             const float4* __restrict__ x2p,
                                             const ushort_t* __restrict__ p2t,
                                             ushort_t* __restrict__ Xc) {
  __shared__ float4 xs[S_];          // 32 KB
  __shared__ float md[128 * 8 * 3];  // 12 KB
  __shared__ int   mi[128 * 8 * 3];  // 12 KB
  __shared__ float nrmsh[128];
  __shared__ float wsh[128 * 3];
  __shared__ int   ish[128 * 3];
  int t = threadIdx.x;
  int q0 = blockIdx.x * 128;
  int b = q0 >> 13;
  int n0 = q0 & (N_ - 1);
  for (int l = t; l < S_; l += 256) xs[l] = x2p[(size_t)b * S_ + l];
  int sub = t >> 5;
  int qg = t & 31;
  float qx[4], qy[4], qz[4];
  float c0[4], c1[4], c2[4];
  int i0[4], i1[4], i2[4];
#pragma unroll
  for (int j = 0; j < 4; ++j) {
    int n = n0 + qg * 4 + j;
    qx[j] = xyz1[((size_t)b * 3 + 0) * N_ + n];
    qy[j] = xyz1[((size_t)b * 3 + 1) * N_ + n];
    qz[j] = xyz1[((size_t)b * 3 + 2) * N_ + n];
    c0[j] = 3e38f; c1[j] = 3e38f; c2[j] = 3e38f;
    i0[j] = 0; i1[j] = 0; i2[j] = 0;
    if (sub == 0) nrmsh[qg * 4 + j] = qx[j] * qx[j] + qy[j] * qy[j] + qz[j] * qz[j];
  }
  __syncthreads();
  int sbase = sub * 256;
  // e = 0.5*|x2|^2 - dot(x1,x2); true dist d = 2e + |x1|^2 (monotone in e)
#pragma unroll 4
  for (int i = 0; i < 256; ++i) {
    float4 P = xs[sbase + i];
    int s = sbase + i;
#pragma unroll
    for (int j = 0; j < 4; ++j) {
      float e = fmaf(-qx[j], P.x, fmaf(-qy[j], P.y, fmaf(-qz[j], P.z, P.w)));
      bool l0 = e < c0[j], l1 = e < c1[j], l2 = e < c2[j];
      float nf0 = fminf(e, c0[j]);
      float nf1 = __builtin_amdgcn_fmed3f(e, c0[j], c1[j]);
      float nf2 = __builtin_amdgcn_fmed3f(e, c1[j], c2[j]);
      int ni2 = l1 ? i1[j] : (l2 ? s : i2[j]);
      int ni1 = l0 ? i0[j] : (l1 ? s : i1[j]);
      int ni0 = l0 ? s : i0[j];
      c0[j] = nf0; c1[j] = nf1; c2[j] = nf2;
      i0[j] = ni0; i1[j] = ni1; i2[j] = ni2;
    }
  }
#pragma unroll
  for (int j = 0; j < 4; ++j) {
    int base = ((qg * 4 + j) * 8 + sub) * 3;
    md[base + 0] = c0[j]; md[base + 1] = c1[j]; md[base + 2] = c2[j];
    mi[base + 0] = i0[j]; mi[base + 1] = i1[j]; mi[base + 2] = i2[j];
  }
  __syncthreads();
  if (t < 128) {
    int base = t * 24;
    float a0 = md[base], a1 = md[base + 1], a2 = md[base + 2];
    int j0 = mi[base], j1 = mi[base + 1], j2 = mi[base + 2];
#pragma unroll
    for (int sc = 1; sc < 8; ++sc) {
#pragma unroll
      for (int k = 0; k < 3; ++k) {
        float e = md[base + sc * 3 + k];
        int s = mi[base + sc * 3 + k];
        bool l0 = e < a0, l1 = e < a1, l2 = e < a2;
        float nf0 = fminf(e, a0);
        float nf1 = __builtin_amdgcn_fmed3f(e, a0, a1);
        float nf2 = __builtin_amdgcn_fmed3f(e, a1, a2);
        j2 = l1 ? j1 : (l2 ? s : j2);
        j1 = l0 ? j0 : (l1 ? s : j1);
        j0 = l0 ? s : j0;
        a0 = nf0; a1 = nf1; a2 = nf2;
      }
    }
    float nrm1 = nrmsh[t];
    float dd0 = fmaf(2.f, a0, nrm1);
    float dd1 = fmaf(2.f, a1, nrm1);
    float dd2 = fmaf(2.f, a2, nrm1);
    float r0 = 1.f / (dd0 + 1e-8f);
    float r1 = 1.f / (dd1 + 1e-8f);
    float r2 = 1.f / (dd2 + 1e-8f);
    float rs = 1.f / (r0 + r1 + r2);
    wsh[t * 3 + 0] = r0 * rs; wsh[t * 3 + 1] = r1 * rs; wsh[t * 3 + 2] = r2 * rs;
    ish[t * 3 + 0] = j0; ish[t * 3 + 1] = j1; ish[t * 3 + 2] = j2;
  }
  __syncthreads();
  // gather: 4 queries in parallel, 64 lanes x 4 channels each
  int lane = t & 63, grp = t >> 6;
  size_t sbase2 = (size_t)b * S_;
#pragma unroll 2
  for (int it = 0; it < 32; ++it) {
    int ql = it * 4 + grp;
    int q = q0 + ql;
    float w0 = wsh[ql * 3 + 0], w1 = wsh[ql * 3 + 1], w2 = wsh[ql * 3 + 2];
    int j0 = ish[ql * 3 + 0], j1 = ish[ql * 3 + 1], j2 = ish[ql * 3 + 2];
    ushort4 a0 = *(const ushort4*)&p2t[(sbase2 + j0) * D2_ + lane * 4];
    ushort4 a1 = *(const ushort4*)&p2t[(sbase2 + j1) * D2_ + lane * 4];
    ushort4 a2 = *(const ushort4*)&p2t[(sbase2 + j2) * D2_ + lane * 4];
    ushort4 o;
    o.x = f2bf(w0 * bf2f(a0.x) + w1 * bf2f(a1.x) + w2 * bf2f(a2.x));
    o.y = f2bf(w0 * bf2f(a0.y) + w1 * bf2f(a1.y) + w2 * bf2f(a2.y));
    o.z = f2bf(w0 * bf2f(a0.z) + w1 * bf2f(a1.z) + w2 * bf2f(a2.z));
    o.w = f2bf(w0 * bf2f(a0.w) + w1 * bf2f(a1.w) + w2 * bf2f(a2.w));
    *(ushort4*)&Xc[(size_t)q * INCH_ + D1_ + lane * 4] = o;
  }
}

// ---------- bf16 MFMA GEMM: C[M,Nout] = A[M,K] * W[Nout,K]^T (fp32 out) ----------
__global__ __launch_bounds__(256) void k_gemm(const ushort_t* __restrict__ A,
                                              const ushort_t* __restrict__ Bw,
                                              float* __restrict__ Cc,
                                              int M, int K, int Nout) {
  __shared__ __align__(16) ushort_t As[128 * 32];
  __shared__ __align__(16) ushort_t Bs[128 * 32];
  const int tid = threadIdx.x;
  const int m0 = blockIdx.x * 128;
  const int n0 = blockIdx.y * 128;
  const int wave = tid >> 6;
  const int lane = tid & 63;
  const int quad = lane >> 4;
  const int l16 = lane & 15;
  const int wrow = (wave >> 1) * 64;
  const int wcol = (wave & 1) * 64;
  floatx4 acc[4][4];
#pragma unroll
  for (int i = 0; i < 4; i++)
#pragma unroll
    for (int j = 0; j < 4; j++) acc[i][j] = (floatx4){0.f, 0.f, 0.f, 0.f};

  for (int k0 = 0; k0 < K; k0 += 32) {
#pragma unroll
    for (int it = 0; it < 2; it++) {
      int l = tid + it * 256;
      int row = l >> 2, seg = l & 3;
      *(uint4*)&As[row * 32 + seg * 8] = *(const uint4*)&A[(size_t)(m0 + row) * K + k0 + seg * 8];
      *(uint4*)&Bs[row * 32 + seg * 8] = *(const uint4*)&Bw[(size_t)(n0 + row) * K + k0 + seg * 8];
    }
    __syncthreads();
    bf16x8 af[4], bfr[4];
#pragma unroll
    for (int mt = 0; mt < 4; mt++) af[mt] = *(const bf16x8*)&As[(wrow + mt * 16 + l16) * 32 + quad * 8];
#pragma unroll
    for (int nt = 0; nt < 4; nt++) bfr[nt] = *(const bf16x8*)&Bs[(wcol + nt * 16 + l16) * 32 + quad * 8];
#pragma unroll
    for (int mt = 0; mt < 4; mt++)
#pragma unroll
      for (int nt = 0; nt < 4; nt++)
        acc[mt][nt] = __builtin_amdgcn_mfma_f32_16x16x32_bf16(af[mt], bfr[nt], acc[mt][nt], 0, 0, 0);
    __syncthreads();
  }
#pragma unroll
  for (int mt = 0; mt < 4; mt++) {
#pragma unroll
    for (int i = 0; i < 4; i++) {
      int row = m0 + wrow + mt * 16 + quad * 4 + i;
#pragma unroll
      for (int nt = 0; nt < 4; nt++) {
        int col = n0 + wcol + nt * 16 + l16;
        Cc[(size_t)row * Nout + col] = acc[mt][nt][i];
      }
    }
  }
}

// ---------- BN stats: per-channel sum / sumsq ----------
__global__ __launch_bounds__(256) void k_stats(const float* __restrict__ Y,
                                               float* __restrict__ sum,
                                               float* __restrict__ ssq,
                                               int C, int rowsPerBlock) {
  int tid = threadIdx.x;
  int c = tid & (C - 1);
  int rsub = tid / C;
  int step = 256 / C;
  int r0 = blockIdx.x * rowsPerBlock;
  float s = 0.f, s2 = 0.f;
  for (int r = rsub; r < rowsPerBlock; r += step) {
    float v = Y[(size_t)(r0 + r) * C + c];
    s += v;
    s2 += v * v;
  }
  atomicAdd(&sum[c], s);
  atomicAdd(&ssq[c], s2);
}

__global__ void k_finalize(const float* __restrict__ sum, const float* __restrict__ ssq,
                           const float* __restrict__ g, const float* __restrict__ be,
                           float* __restrict__ scale, float* __restrict__ shift,
                           float inv_count) {
  int c = threadIdx.x;
  float mean = sum[c] * inv_count;
  float var = ssq[c] * inv_count - mean * mean;
  float sc = rsqrtf(var + 1e-5f) * g[c];
  scale[c] = sc;
  shift[c] = be[c] - mean * sc;
}

// ---------- normalize + relu -> bf16 (layer 1 activations) ----------
__global__ __launch_bounds__(256) void k_norm_relu(const float4* __restrict__ Y,
                                                   const float* __restrict__ scale,
                                                   const float* __restrict__ shift,
                                                   ushort_t* __restrict__ X) {
  int idx = blockIdx.x * 256 + threadIdx.x;  // 4194304 float4s
  float4 y = Y[idx];
  int c = (idx & 63) * 4;  // 256 channels / 4 per float4
  float v0 = fmaxf(fmaf(y.x, scale[c + 0], shift[c + 0]), 0.f);
  float v1 = fmaxf(fmaf(y.y, scale[c + 1], shift[c + 1]), 0.f);
  float v2 = fmaxf(fmaf(y.z, scale[c + 2], shift[c + 2]), 0.f);
  float v3 = fmaxf(fmaf(y.w, scale[c + 3], shift[c + 3]), 0.f);
  ushort4 o;
  o.x = f2bf(v0); o.y = f2bf(v1); o.z = f2bf(v2); o.w = f2bf(v3);
  *(ushort4*)&X[(size_t)idx * 4] = o;
}

// ---------- final: BN + relu + transpose to [B,128,N] ----------
__global__ __launch_bounds__(256) void k_out(const float* __restrict__ Y2,
                                             const float* __restrict__ scale,
                                             const float* __restrict__ shift,
                                             float* __restrict__ out) {
  __shared__ float t[64 * 129];  // 33 KB
  int tid = threadIdx.x;
  int p0 = blockIdx.x * 64;  // 1024 blocks
  int b = p0 >> 13;
  int n0 = p0 & (N_ - 1);
#pragma unroll
  for (int it = 0; it < 32; it++) {
    int idx = it * 256 + tid;
    int r = idx >> 7, c = idx & 127;
    t[r * 129 + c] = Y2[(size_t)(p0 + r) * 128 + c];
  }
  __syncthreads();
#pragma unroll
  for (int it = 0; it < 32; it++) {
    int idx = it * 256 + tid;
    int j = idx & 63, c = idx >> 6;
    float v = fmaxf(fmaf(t[j * 129 + c], scale[c], shift[c]), 0.f);
    out[((size_t)(b * 128 + c)) * N_ + n0 + j] = v;
  }
}

extern "C" void kernel_launch(void* const* d_in, const int* in_sizes, int n_in,
                              void* d_out, int out_size, void* d_ws, size_t ws_size,
                              hipStream_t stream) {
  const float* xyz1    = (const float*)d_in[0];
  const float* xyz2    = (const float*)d_in[1];
  const float* points1 = (const float*)d_in[2];
  const float* points2 = (const float*)d_in[3];
  const float* W0 = (const float*)d_in[4];
  const float* g0 = (const float*)d_in[6];
  const float* be0 = (const float*)d_in[7];
  const float* W1 = (const float*)d_in[8];
  const float* g1 = (const float*)d_in[10];
  const float* be1 = (const float*)d_in[11];
  float* out = (float*)d_out;
  char* ws = (char*)d_ws;

  float* sum0   = (float*)(ws + OFF_STATS);
  float* ssq0   = sum0 + 256;
  float* sum1   = sum0 + 512;
  float* ssq1   = sum0 + 640;
  float* scale0 = sum0 + 768;
  float* shift0 = sum0 + 1024;
  float* scale1 = sum0 + 1280;
  float* shift1 = sum0 + 1408;
  ushort_t* W0b = (ushort_t*)(ws + OFF_W0B);
  ushort_t* W1b = (ushort_t*)(ws + OFF_W1B);
  float4* x2p   = (float4*)(ws + OFF_X2P);
  ushort_t* p2t = (ushort_t*)(ws + OFF_P2T);
  ushort_t* Xc  = (ushort_t*)(ws + OFF_XC);
  ushort_t* X1  = (ushort_t*)(ws + OFF_XC);   // overlays Xc (dead after GEMM1)
  float* Y1     = (float*)(ws + OFF_Y1);
  float* Y2     = (float*)(ws + OFF_Y1);       // overlays Y1 (dead after norm)

  hipMemsetAsync(ws + OFF_STATS, 0, 6144, stream);
  k_prep_weights<<<512, 256, 0, stream>>>(W0, W1, W0b, W1b);
  k_pack_xyz2<<<64, 256, 0, stream>>>(xyz2, x2p);
  k_tr_p2<<<dim3(64, 8, 8), dim3(32, 8), 0, stream>>>(points2, p2t);
  k_tr_p1<<<dim3(256, 4, 8), dim3(32, 8), 0, stream>>>(points1, Xc);
  k_knn<<<512, 256, 0, stream>>>(xyz1, x2p, p2t, Xc);
  k_gemm<<<dim3(512, 2), 256, 0, stream>>>(Xc, W0b, Y1, M_, 384, 256);
  k_stats<<<256, 256, 0, stream>>>(Y1, sum0, ssq0, 256, 256);
  k_finalize<<<1, 256, 0, stream>>>(sum0, ssq0, g0, be0, scale0, shift0, 1.f / 65536.f);
  k_norm_relu<<<16384, 256, 0, stream>>>((const float4*)Y1, scale0, shift0, X1);
  k_gemm<<<dim3(512, 1), 256, 0, stream>>>(X1, W1b, Y2, M_, 256, 128);
  k_stats<<<256, 256, 0, stream>>>(Y2, sum1, ssq1, 128, 256);
  k_finalize<<<1, 128, 0, stream>>>(sum1, ssq1, g1, be1, scale1, shift1, 1.f / 65536.f);
  k_out<<<1024, 256, 0, stream>>>(Y2, scale1, shift1, out);
}

// Round 3
// 351.676 us; speedup vs baseline: 2.2127x; 1.1618x over previous
//
#include <hip/hip_runtime.h>

typedef unsigned short ushort_t;
typedef __bf16 bf16x8 __attribute__((ext_vector_type(8)));
typedef float floatx4 __attribute__((ext_vector_type(4)));

#define B_ 8
#define N_ 8192
#define S_ 2048
#define D1_ 128
#define D2_ 256
#define INCH_ 384
#define M_ 65536  // B*N

// ---------- workspace layout (bytes) ----------
constexpr size_t OFF_STATS = 0;          // 6144 B used
constexpr size_t OFF_W0B   = 8192;       // 256*384*2 = 196608
constexpr size_t OFF_W1B   = 204800;     // 128*256*2 = 65536
constexpr size_t OFF_X2P   = 270336;     // 8*2048*16 = 262144 (float4 x,y,z,0.5*|x|^2)
constexpr size_t OFF_P2T   = 532480;     // 8*2048*256*2 = 8388608 bf16
constexpr size_t OFF_XC    = 8921088;    // 65536*384*2 = 50331648 bf16 ; X1 overlays this later
constexpr size_t OFF_Y1    = 59252736;   // 65536*256*4 = 67108864 f32  ; Y2 overlays this later

__device__ __forceinline__ ushort_t f2bf(float f) {
  unsigned int u = __float_as_uint(f);
  unsigned int r = u + 0x7fffu + ((u >> 16) & 1u);
  return (ushort_t)(r >> 16);
}
__device__ __forceinline__ float bf2f(ushort_t h) {
  return __uint_as_float(((unsigned int)h) << 16);
}

// insert (e,s) into sorted top-3 (c0<=c1<=c2); strict < keeps existing on ties
__device__ __forceinline__ void ins3(float e, int s,
                                     float& c0, float& c1, float& c2,
                                     int& i0, int& i1, int& i2) {
  bool l0 = e < c0, l1 = e < c1, l2 = e < c2;
  float nf0 = fminf(e, c0);
  float nf1 = __builtin_amdgcn_fmed3f(e, c0, c1);
  float nf2 = __builtin_amdgcn_fmed3f(e, c1, c2);
  i2 = l1 ? i1 : (l2 ? s : i2);
  i1 = l0 ? i0 : (l1 ? s : i1);
  i0 = l0 ? s : i0;
  c0 = nf0; c1 = nf1; c2 = nf2;
}

// ---------- weights fp32 -> bf16 ----------
__global__ __launch_bounds__(256) void k_prep_weights(const float* __restrict__ W0,
                                                      const float* __restrict__ W1,
                                                      ushort_t* __restrict__ W0b,
                                                      ushort_t* __restrict__ W1b) {
  int i = blockIdx.x * 256 + threadIdx.x;
  if (i < 98304) W0b[i] = f2bf(W0[i]);
  else           W1b[i - 98304] = f2bf(W1[i - 98304]);
}

// ---------- pack xyz2 -> (x,y,z,0.5*|x|^2) ----------
__global__ __launch_bounds__(256) void k_pack_xyz2(const float* __restrict__ xyz2,
                                                   float4* __restrict__ x2p) {
  int idx = blockIdx.x * 256 + threadIdx.x;  // 16384
  int b = idx >> 11, s = idx & (S_ - 1);
  const float* base = xyz2 + (size_t)b * 3 * S_;
  float x = base[s], y = base[S_ + s], z = base[2 * S_ + s];
  x2p[idx] = make_float4(x, y, z, 0.5f * (x * x + y * y + z * z));
}

// ---------- transpose points2 [B,256,S] -> p2t bf16 [B,S,256] ----------
__global__ void k_tr_p2(const float* __restrict__ P2, ushort_t* __restrict__ p2t) {
  __shared__ float t[32][33];
  int b = blockIdx.z;
  int s0 = blockIdx.x * 32;
  int c0 = blockIdx.y * 32;
  int tx = threadIdx.x, ty = threadIdx.y;  // (32,8)
#pragma unroll
  for (int j = 0; j < 4; j++) {
    int c = c0 + ty + j * 8;
    t[ty + j * 8][tx] = P2[((size_t)b * D2_ + c) * S_ + s0 + tx];
  }
  __syncthreads();
#pragma unroll
  for (int j = 0; j < 4; j++) {
    int s = s0 + ty + j * 8;
    p2t[((size_t)b * S_ + s) * D2_ + c0 + tx] = f2bf(t[tx][ty + j * 8]);
  }
}

// ---------- transpose points1 [B,128,N] -> Xc cols 0..127 (bf16, row stride 384) ----------
__global__ void k_tr_p1(const float* __restrict__ P1, ushort_t* __restrict__ Xc) {
  __shared__ float t[32][33];
  int b = blockIdx.z;
  int n0 = blockIdx.x * 32;
  int c0 = blockIdx.y * 32;
  int tx = threadIdx.x, ty = threadIdx.y;
#pragma unroll
  for (int j = 0; j < 4; j++) {
    int c = c0 + ty + j * 8;
    t[ty + j * 8][tx] = P1[((size_t)b * D1_ + c) * N_ + n0 + tx];
  }
  __syncthreads();
#pragma unroll
  for (int j = 0; j < 4; j++) {
    int n = n0 + ty + j * 8;
    Xc[((size_t)b * N_ + n) * INCH_ + c0 + tx] = f2bf(t[tx][ty + j * 8]);
  }
}

// ---------- kNN + interpolate: 512 blocks, 128 queries/block ----------
// sub = t&7 (S-chunk of 256 pts, all 8 subs of a query group in ONE wave),
// qg = t>>3 (32 groups x 4 queries). Merge via shfl_xor; no LDS scratch.
__global__ __launch_bounds__(256, 4) void k_knn(const float* __restrict__ xyz1,
                                                const float4* __restrict__ x2p,
                                                const ushort_t* __restrict__ p2t,
                                                ushort_t* __restrict__ Xc) {
  __shared__ float4 xs[S_];          // 32 KB
  __shared__ float wsh[128 * 3];
  __shared__ int   ish[128 * 3];
  int t = threadIdx.x;
  int q0 = blockIdx.x * 128;
  int b = q0 >> 13;
  int n0 = q0 & (N_ - 1);
  for (int l = t; l < S_; l += 256) xs[l] = x2p[(size_t)b * S_ + l];
  int sub = t & 7;
  int qg = t >> 3;
  float qx[4], qy[4], qz[4];
  float c0[4], c1[4], c2[4];
  int i0[4], i1[4], i2[4];
#pragma unroll
  for (int j = 0; j < 4; ++j) {
    int n = n0 + qg * 4 + j;
    qx[j] = xyz1[((size_t)b * 3 + 0) * N_ + n];
    qy[j] = xyz1[((size_t)b * 3 + 1) * N_ + n];
    qz[j] = xyz1[((size_t)b * 3 + 2) * N_ + n];
    c0[j] = 3e38f; c1[j] = 3e38f; c2[j] = 3e38f;
    i0[j] = 0; i1[j] = 0; i2[j] = 0;
  }
  __syncthreads();
  // e = 0.5*|x2|^2 - dot(x1,x2); true dist d = 2e + |x1|^2 (monotone in e)
  int sbase = sub << 8;
  int stag = sub * 33;  // stagger start so the 8 sub-addresses hit disjoint bank groups
#pragma unroll 2
  for (int i = 0; i < 256; ++i) {
    int ii = (i + stag) & 255;
    int s = sbase + ii;
    float4 P = xs[s];
#pragma unroll
    for (int j = 0; j < 4; ++j) {
      float e = fmaf(-qx[j], P.x, fmaf(-qy[j], P.y, fmaf(-qz[j], P.z, P.w)));
      ins3(e, s, c0[j], c1[j], c2[j], i0[j], i1[j], i2[j]);
    }
  }
  // merge the 8 sub-lists within the wave (lanes differ only in low-3 bits)
#pragma unroll
  for (int d = 1; d < 8; d <<= 1) {
#pragma unroll
    for (int j = 0; j < 4; ++j) {
      float e0 = __shfl_xor(c0[j], d); int s0 = __shfl_xor(i0[j], d);
      float e1 = __shfl_xor(c1[j], d); int s1 = __shfl_xor(i1[j], d);
      float e2 = __shfl_xor(c2[j], d); int s2 = __shfl_xor(i2[j], d);
      ins3(e0, s0, c0[j], c1[j], c2[j], i0[j], i1[j], i2[j]);
      ins3(e1, s1, c0[j], c1[j], c2[j], i0[j], i1[j], i2[j]);
      ins3(e2, s2, c0[j], c1[j], c2[j], i0[j], i1[j], i2[j]);
    }
  }
  if (sub == 0) {
#pragma unroll
    for (int j = 0; j < 4; ++j) {
      int ql = qg * 4 + j;
      float nrm1 = qx[j] * qx[j] + qy[j] * qy[j] + qz[j] * qz[j];
      float dd0 = fmaf(2.f, c0[j], nrm1);
      float dd1 = fmaf(2.f, c1[j], nrm1);
      float dd2 = fmaf(2.f, c2[j], nrm1);
      float r0 = 1.f / (dd0 + 1e-8f);
      float r1 = 1.f / (dd1 + 1e-8f);
      float r2 = 1.f / (dd2 + 1e-8f);
      float rs = 1.f / (r0 + r1 + r2);
      wsh[ql * 3 + 0] = r0 * rs; wsh[ql * 3 + 1] = r1 * rs; wsh[ql * 3 + 2] = r2 * rs;
      ish[ql * 3 + 0] = i0[j]; ish[ql * 3 + 1] = i1[j]; ish[ql * 3 + 2] = i2[j];
    }
  }
  __syncthreads();
  // gather: 4 queries in parallel, 64 lanes x 4 channels each
  int lane = t & 63, grp = t >> 6;
  size_t sbase2 = (size_t)b * S_;
#pragma unroll 2
  for (int it = 0; it < 32; ++it) {
    int ql = it * 4 + grp;
    int q = q0 + ql;
    float w0 = wsh[ql * 3 + 0], w1 = wsh[ql * 3 + 1], w2 = wsh[ql * 3 + 2];
    int j0 = ish[ql * 3 + 0], j1 = ish[ql * 3 + 1], j2 = ish[ql * 3 + 2];
    ushort4 a0 = *(const ushort4*)&p2t[(sbase2 + j0) * D2_ + lane * 4];
    ushort4 a1 = *(const ushort4*)&p2t[(sbase2 + j1) * D2_ + lane * 4];
    ushort4 a2 = *(const ushort4*)&p2t[(sbase2 + j2) * D2_ + lane * 4];
    ushort4 o;
    o.x = f2bf(w0 * bf2f(a0.x) + w1 * bf2f(a1.x) + w2 * bf2f(a2.x));
    o.y = f2bf(w0 * bf2f(a0.y) + w1 * bf2f(a1.y) + w2 * bf2f(a2.y));
    o.z = f2bf(w0 * bf2f(a0.z) + w1 * bf2f(a1.z) + w2 * bf2f(a2.z));
    o.w = f2bf(w0 * bf2f(a0.w) + w1 * bf2f(a1.w) + w2 * bf2f(a2.w));
    *(ushort4*)&Xc[(size_t)q * INCH_ + D1_ + lane * 4] = o;
  }
}

// ---------- bf16 MFMA GEMM + fused BN-stats epilogue ----------
__global__ __launch_bounds__(256) void k_gemm(const ushort_t* __restrict__ A,
                                              const ushort_t* __restrict__ Bw,
                                              float* __restrict__ Cc,
                                              float* __restrict__ sum,
                                              float* __restrict__ ssq,
                                              int M, int K, int Nout) {
  __shared__ __align__(16) ushort_t As[128 * 32];
  __shared__ __align__(16) ushort_t Bs[128 * 32];
  const int tid = threadIdx.x;
  const int m0 = blockIdx.x * 128;
  const int n0 = blockIdx.y * 128;
  const int wave = tid >> 6;
  const int lane = tid & 63;
  const int quad = lane >> 4;
  const int l16 = lane & 15;
  const int wrow = (wave >> 1) * 64;
  const int wcol = (wave & 1) * 64;
  floatx4 acc[4][4];
#pragma unroll
  for (int i = 0; i < 4; i++)
#pragma unroll
    for (int j = 0; j < 4; j++) acc[i][j] = (floatx4){0.f, 0.f, 0.f, 0.f};

  for (int k0 = 0; k0 < K; k0 += 32) {
#pragma unroll
    for (int it = 0; it < 2; it++) {
      int l = tid + it * 256;
      int row = l >> 2, seg = l & 3;
      *(uint4*)&As[row * 32 + seg * 8] = *(const uint4*)&A[(size_t)(m0 + row) * K + k0 + seg * 8];
      *(uint4*)&Bs[row * 32 + seg * 8] = *(const uint4*)&Bw[(size_t)(n0 + row) * K + k0 + seg * 8];
    }
    __syncthreads();
    bf16x8 af[4], bfr[4];
#pragma unroll
    for (int mt = 0; mt < 4; mt++) af[mt] = *(const bf16x8*)&As[(wrow + mt * 16 + l16) * 32 + quad * 8];
#pragma unroll
    for (int nt = 0; nt < 4; nt++) bfr[nt] = *(const bf16x8*)&Bs[(wcol + nt * 16 + l16) * 32 + quad * 8];
#pragma unroll
    for (int mt = 0; mt < 4; mt++)
#pragma unroll
      for (int nt = 0; nt < 4; nt++)
        acc[mt][nt] = __builtin_amdgcn_mfma_f32_16x16x32_bf16(af[mt], bfr[nt], acc[mt][nt], 0, 0, 0);
    __syncthreads();
  }
#pragma unroll
  for (int mt = 0; mt < 4; mt++) {
#pragma unroll
    for (int i = 0; i < 4; i++) {
      int row = m0 + wrow + mt * 16 + quad * 4 + i;
#pragma unroll
      for (int nt = 0; nt < 4; nt++) {
        int col = n0 + wcol + nt * 16 + l16;
        Cc[(size_t)row * Nout + col] = acc[mt][nt][i];
      }
    }
  }
  // fused BN stats: per-column sum/sumsq over this block's 128 rows
#pragma unroll
  for (int nt = 0; nt < 4; nt++) {
    float s = 0.f, s2 = 0.f;
#pragma unroll
    for (int mt = 0; mt < 4; mt++)
#pragma unroll
      for (int i = 0; i < 4; i++) {
        float v = acc[mt][nt][i];
        s += v;
        s2 = fmaf(v, v, s2);
      }
    s += __shfl_xor(s, 16);  s2 += __shfl_xor(s2, 16);
    s += __shfl_xor(s, 32);  s2 += __shfl_xor(s2, 32);
    if (quad == 0) {
      int col = n0 + wcol + nt * 16 + l16;
      atomicAdd(&sum[col], s);
      atomicAdd(&ssq[col], s2);
    }
  }
}

__global__ void k_finalize(const float* __restrict__ sum, const float* __restrict__ ssq,
                           const float* __restrict__ g, const float* __restrict__ be,
                           float* __restrict__ scale, float* __restrict__ shift,
                           float inv_count) {
  int c = threadIdx.x;
  float mean = sum[c] * inv_count;
  float var = ssq[c] * inv_count - mean * mean;
  float sc = rsqrtf(var + 1e-5f) * g[c];
  scale[c] = sc;
  shift[c] = be[c] - mean * sc;
}

// ---------- normalize + relu -> bf16 (layer 1 activations) ----------
__global__ __launch_bounds__(256) void k_norm_relu(const float4* __restrict__ Y,
                                                   const float* __restrict__ scale,
                                                   const float* __restrict__ shift,
                                                   ushort_t* __restrict__ X) {
  int idx = blockIdx.x * 256 + threadIdx.x;  // 4194304 float4s
  float4 y = Y[idx];
  int c = (idx & 63) * 4;
  float v0 = fmaxf(fmaf(y.x, scale[c + 0], shift[c + 0]), 0.f);
  float v1 = fmaxf(fmaf(y.y, scale[c + 1], shift[c + 1]), 0.f);
  float v2 = fmaxf(fmaf(y.z, scale[c + 2], shift[c + 2]), 0.f);
  float v3 = fmaxf(fmaf(y.w, scale[c + 3], shift[c + 3]), 0.f);
  ushort4 o;
  o.x = f2bf(v0); o.y = f2bf(v1); o.z = f2bf(v2); o.w = f2bf(v3);
  *(ushort4*)&X[(size_t)idx * 4] = o;
}

// ---------- final: BN + relu + transpose to [B,128,N] ----------
__global__ __launch_bounds__(256) void k_out(const float* __restrict__ Y2,
                                             const float* __restrict__ scale,
                                             const float* __restrict__ shift,
                                             float* __restrict__ out) {
  __shared__ float t[64 * 129];
  int tid = threadIdx.x;
  int p0 = blockIdx.x * 64;  // 1024 blocks
  int b = p0 >> 13;
  int n0 = p0 & (N_ - 1);
#pragma unroll
  for (int it = 0; it < 32; it++) {
    int idx = it * 256 + tid;
    int r = idx >> 7, c = idx & 127;
    t[r * 129 + c] = Y2[(size_t)(p0 + r) * 128 + c];
  }
  __syncthreads();
#pragma unroll
  for (int it = 0; it < 32; it++) {
    int idx = it * 256 + tid;
    int j = idx & 63, c = idx >> 6;
    float v = fmaxf(fmaf(t[j * 129 + c], scale[c], shift[c]), 0.f);
    out[((size_t)(b * 128 + c)) * N_ + n0 + j] = v;
  }
}

extern "C" void kernel_launch(void* const* d_in, const int* in_sizes, int n_in,
                              void* d_out, int out_size, void* d_ws, size_t ws_size,
                              hipStream_t stream) {
  const float* xyz1    = (const float*)d_in[0];
  const float* xyz2    = (const float*)d_in[1];
  const float* points1 = (const float*)d_in[2];
  const float* points2 = (const float*)d_in[3];
  const float* W0 = (const float*)d_in[4];
  const float* g0 = (const float*)d_in[6];
  const float* be0 = (const float*)d_in[7];
  const float* W1 = (const float*)d_in[8];
  const float* g1 = (const float*)d_in[10];
  const float* be1 = (const float*)d_in[11];
  float* out = (float*)d_out;
  char* ws = (char*)d_ws;

  float* sum0   = (float*)(ws + OFF_STATS);
  float* ssq0   = sum0 + 256;
  float* sum1   = sum0 + 512;
  float* ssq1   = sum0 + 640;
  float* scale0 = sum0 + 768;
  float* shift0 = sum0 + 1024;
  float* scale1 = sum0 + 1280;
  float* shift1 = sum0 + 1408;
  ushort_t* W0b = (ushort_t*)(ws + OFF_W0B);
  ushort_t* W1b = (ushort_t*)(ws + OFF_W1B);
  float4* x2p   = (float4*)(ws + OFF_X2P);
  ushort_t* p2t = (ushort_t*)(ws + OFF_P2T);
  ushort_t* Xc  = (ushort_t*)(ws + OFF_XC);
  ushort_t* X1  = (ushort_t*)(ws + OFF_XC);   // overlays Xc (dead after GEMM1)
  float* Y1     = (float*)(ws + OFF_Y1);
  float* Y2     = (float*)(ws + OFF_Y1);       // overlays Y1 (dead after norm)

  hipMemsetAsync(ws + OFF_STATS, 0, 6144, stream);
  k_prep_weights<<<512, 256, 0, stream>>>(W0, W1, W0b, W1b);
  k_pack_xyz2<<<64, 256, 0, stream>>>(xyz2, x2p);
  k_tr_p2<<<dim3(64, 8, 8), dim3(32, 8), 0, stream>>>(points2, p2t);
  k_tr_p1<<<dim3(256, 4, 8), dim3(32, 8), 0, stream>>>(points1, Xc);
  k_knn<<<512, 256, 0, stream>>>(xyz1, x2p, p2t, Xc);
  k_gemm<<<dim3(512, 2), 256, 0, stream>>>(Xc, W0b, Y1, sum0, ssq0, M_, 384, 256);
  k_finalize<<<1, 256, 0, stream>>>(sum0, ssq0, g0, be0, scale0, shift0, 1.f / 65536.f);
  k_norm_relu<<<16384, 256, 0, stream>>>((const float4*)Y1, scale0, shift0, X1);
  k_gemm<<<dim3(512, 1), 256, 0, stream>>>(X1, W1b, Y2, sum1, ssq1, M_, 256, 128);
  k_finalize<<<1, 128, 0, stream>>>(sum1, ssq1, g1, be1, scale1, shift1, 1.f / 65536.f);
  k_out<<<1024, 256, 0, stream>>>(Y2, scale1, shift1, out);
}

// Round 4
// 326.161 us; speedup vs baseline: 2.3858x; 1.0782x over previous
//
#include <hip/hip_runtime.h>

typedef unsigned short ushort_t;
typedef __bf16 bf16x8 __attribute__((ext_vector_type(8)));
typedef float floatx4 __attribute__((ext_vector_type(4)));

#define B_ 8
#define N_ 8192
#define S_ 2048
#define D1_ 128
#define D2_ 256
#define INCH_ 384
#define M_ 65536  // B*N

// ---------- workspace layout (bytes) ----------
constexpr size_t OFF_STATS = 0;          // 6144 B used
constexpr size_t OFF_W0B   = 8192;       // 256*384*2 = 196608
constexpr size_t OFF_W1B   = 204800;     // 128*256*2 = 65536
constexpr size_t OFF_X2P   = 270336;     // 8*2048*16 = 262144 (float4 x,y,z,0.5*|x|^2)
constexpr size_t OFF_P2T   = 532480;     // 8*2048*256*2 = 8388608 bf16
constexpr size_t OFF_XC    = 8921088;    // 65536*384*2 = 50331648 bf16 ; X1 overlays this later
constexpr size_t OFF_Y1    = 59252736;   // 65536*256*4 = 67108864 f32  ; Y2 overlays this later

__device__ __forceinline__ ushort_t f2bf(float f) {
  unsigned int u = __float_as_uint(f);
  unsigned int r = u + 0x7fffu + ((u >> 16) & 1u);
  return (ushort_t)(r >> 16);
}
__device__ __forceinline__ float bf2f(ushort_t h) {
  return __uint_as_float(((unsigned int)h) << 16);
}

// insert (e,s) into sorted top-3 (c0<=c1<=c2); strict < keeps existing on ties
__device__ __forceinline__ void ins3(float e, int s,
                                     float& c0, float& c1, float& c2,
                                     int& i0, int& i1, int& i2) {
  bool l0 = e < c0, l1 = e < c1, l2 = e < c2;
  float nf0 = fminf(e, c0);
  float nf1 = __builtin_amdgcn_fmed3f(e, c0, c1);
  float nf2 = __builtin_amdgcn_fmed3f(e, c1, c2);
  i2 = l1 ? i1 : (l2 ? s : i2);
  i1 = l0 ? i0 : (l1 ? s : i1);
  i0 = l0 ? s : i0;
  c0 = nf0; c1 = nf1; c2 = nf2;
}

// ---------- prep: weights fp32->bf16 + pack xyz2 (one launch) ----------
__global__ __launch_bounds__(256) void k_prep(const float* __restrict__ W0,
                                              const float* __restrict__ W1,
                                              const float* __restrict__ xyz2,
                                              ushort_t* __restrict__ W0b,
                                              ushort_t* __restrict__ W1b,
                                              float4* __restrict__ x2p) {
  int i = blockIdx.x * 256 + threadIdx.x;  // grid 576 = (98304+32768+16384)/256
  if (i < 98304) {
    W0b[i] = f2bf(W0[i]);
  } else if (i < 131072) {
    W1b[i - 98304] = f2bf(W1[i - 98304]);
  } else {
    int idx = i - 131072;  // 16384
    int b = idx >> 11, s = idx & (S_ - 1);
    const float* base = xyz2 + (size_t)b * 3 * S_;
    float x = base[s], y = base[S_ + s], z = base[2 * S_ + s];
    x2p[idx] = make_float4(x, y, z, 0.5f * (x * x + y * y + z * z));
  }
}

// ---------- transpose points2 [B,256,S] -> p2t bf16 [B,S,256] ----------
__global__ void k_tr_p2(const float* __restrict__ P2, ushort_t* __restrict__ p2t) {
  __shared__ float t[32][33];
  int b = blockIdx.z;
  int s0 = blockIdx.x * 32;
  int c0 = blockIdx.y * 32;
  int tx = threadIdx.x, ty = threadIdx.y;  // (32,8)
#pragma unroll
  for (int j = 0; j < 4; j++) {
    int c = c0 + ty + j * 8;
    t[ty + j * 8][tx] = P2[((size_t)b * D2_ + c) * S_ + s0 + tx];
  }
  __syncthreads();
#pragma unroll
  for (int j = 0; j < 4; j++) {
    int s = s0 + ty + j * 8;
    p2t[((size_t)b * S_ + s) * D2_ + c0 + tx] = f2bf(t[tx][ty + j * 8]);
  }
}

// ---------- transpose points1 [B,128,N] -> Xc cols 0..127 (bf16, row stride 384) ----------
__global__ void k_tr_p1(const float* __restrict__ P1, ushort_t* __restrict__ Xc) {
  __shared__ float t[32][33];
  int b = blockIdx.z;
  int n0 = blockIdx.x * 32;
  int c0 = blockIdx.y * 32;
  int tx = threadIdx.x, ty = threadIdx.y;
#pragma unroll
  for (int j = 0; j < 4; j++) {
    int c = c0 + ty + j * 8;
    t[ty + j * 8][tx] = P1[((size_t)b * D1_ + c) * N_ + n0 + tx];
  }
  __syncthreads();
#pragma unroll
  for (int j = 0; j < 4; j++) {
    int n = n0 + ty + j * 8;
    Xc[((size_t)b * N_ + n) * INCH_ + c0 + tx] = f2bf(t[tx][ty + j * 8]);
  }
}

// ---------- kNN + interpolate: 512 blocks x 512 threads, 128 queries/block ----------
// sub = t&7 (S-chunk of 256 pts; the 8 subs of a query group live in ONE wave),
// qg = t>>3 in [0,64) x 2 queries. Wave-local shfl_xor merge; no LDS scratch.
// Software-pipelined xs read to keep ds_read latency off the critical path.
__global__ __launch_bounds__(512, 4) void k_knn(const float* __restrict__ xyz1,
                                                const float4* __restrict__ x2p,
                                                const ushort_t* __restrict__ p2t,
                                                ushort_t* __restrict__ Xc) {
  __shared__ float4 xs[S_];          // 32 KB
  __shared__ float wsh[128 * 3];
  __shared__ int   ish[128 * 3];
  int t = threadIdx.x;
  int q0 = blockIdx.x * 128;
  int b = q0 >> 13;
  int n0 = q0 & (N_ - 1);
  for (int l = t; l < S_; l += 512) xs[l] = x2p[(size_t)b * S_ + l];
  int sub = t & 7;
  int qg = t >> 3;
  float qx[2], qy[2], qz[2];
  float c0[2], c1[2], c2[2];
  int i0[2], i1[2], i2[2];
#pragma unroll
  for (int j = 0; j < 2; ++j) {
    int n = n0 + qg * 2 + j;
    qx[j] = xyz1[((size_t)b * 3 + 0) * N_ + n];
    qy[j] = xyz1[((size_t)b * 3 + 1) * N_ + n];
    qz[j] = xyz1[((size_t)b * 3 + 2) * N_ + n];
    c0[j] = 3e38f; c1[j] = 3e38f; c2[j] = 3e38f;
    i0[j] = 0; i1[j] = 0; i2[j] = 0;
  }
  __syncthreads();
  // e = 0.5*|x2|^2 - dot(x1,x2); true dist d = 2e + |x1|^2 (monotone in e)
  int sbase = sub << 8;
  int stag = (sub * 33) & 255;  // stagger: 8 sub-addresses hit disjoint bank groups
  int s = sbase + stag;
  float4 P = xs[s];
#pragma unroll 4
  for (int i = 0; i < 256; ++i) {
    int ii = (i + 1 + stag) & 255;
    int sn = sbase + ii;
    float4 Pn = xs[sn];  // prefetch next point
#pragma unroll
    for (int j = 0; j < 2; ++j) {
      float e = fmaf(-qx[j], P.x, fmaf(-qy[j], P.y, fmaf(-qz[j], P.z, P.w)));
      ins3(e, s, c0[j], c1[j], c2[j], i0[j], i1[j], i2[j]);
    }
    P = Pn; s = sn;
  }
  // merge the 8 sub-lists within the wave (lanes differ only in low-3 bits)
#pragma unroll
  for (int d = 1; d < 8; d <<= 1) {
#pragma unroll
    for (int j = 0; j < 2; ++j) {
      float e0 = __shfl_xor(c0[j], d); int s0 = __shfl_xor(i0[j], d);
      float e1 = __shfl_xor(c1[j], d); int s1 = __shfl_xor(i1[j], d);
      float e2 = __shfl_xor(c2[j], d); int s2 = __shfl_xor(i2[j], d);
      ins3(e0, s0, c0[j], c1[j], c2[j], i0[j], i1[j], i2[j]);
      ins3(e1, s1, c0[j], c1[j], c2[j], i0[j], i1[j], i2[j]);
      ins3(e2, s2, c0[j], c1[j], c2[j], i0[j], i1[j], i2[j]);
    }
  }
  if (sub == 0) {
#pragma unroll
    for (int j = 0; j < 2; ++j) {
      int ql = qg * 2 + j;
      float nrm1 = qx[j] * qx[j] + qy[j] * qy[j] + qz[j] * qz[j];
      float dd0 = fmaf(2.f, c0[j], nrm1);
      float dd1 = fmaf(2.f, c1[j], nrm1);
      float dd2 = fmaf(2.f, c2[j], nrm1);
      float r0 = 1.f / (dd0 + 1e-8f);
      float r1 = 1.f / (dd1 + 1e-8f);
      float r2 = 1.f / (dd2 + 1e-8f);
      float rs = 1.f / (r0 + r1 + r2);
      wsh[ql * 3 + 0] = r0 * rs; wsh[ql * 3 + 1] = r1 * rs; wsh[ql * 3 + 2] = r2 * rs;
      ish[ql * 3 + 0] = i0[j]; ish[ql * 3 + 1] = i1[j]; ish[ql * 3 + 2] = i2[j];
    }
  }
  __syncthreads();
  // gather: 8 queries in parallel (8 waves), 64 lanes x 4 channels each
  int lane = t & 63, grp = t >> 6;
  size_t sbase2 = (size_t)b * S_;
#pragma unroll 2
  for (int it = 0; it < 16; ++it) {
    int ql = it * 8 + grp;
    int q = q0 + ql;
    float w0 = wsh[ql * 3 + 0], w1 = wsh[ql * 3 + 1], w2 = wsh[ql * 3 + 2];
    int j0 = ish[ql * 3 + 0], j1 = ish[ql * 3 + 1], j2 = ish[ql * 3 + 2];
    ushort4 a0 = *(const ushort4*)&p2t[(sbase2 + j0) * D2_ + lane * 4];
    ushort4 a1 = *(const ushort4*)&p2t[(sbase2 + j1) * D2_ + lane * 4];
    ushort4 a2 = *(const ushort4*)&p2t[(sbase2 + j2) * D2_ + lane * 4];
    ushort4 o;
    o.x = f2bf(w0 * bf2f(a0.x) + w1 * bf2f(a1.x) + w2 * bf2f(a2.x));
    o.y = f2bf(w0 * bf2f(a0.y) + w1 * bf2f(a1.y) + w2 * bf2f(a2.y));
    o.z = f2bf(w0 * bf2f(a0.z) + w1 * bf2f(a1.z) + w2 * bf2f(a2.z));
    o.w = f2bf(w0 * bf2f(a0.w) + w1 * bf2f(a1.w) + w2 * bf2f(a2.w));
    *(ushort4*)&Xc[(size_t)q * INCH_ + D1_ + lane * 4] = o;
  }
}

// ---------- bf16 MFMA GEMM + fused BN-stats epilogue ----------
__global__ __launch_bounds__(256) void k_gemm(const ushort_t* __restrict__ A,
                                              const ushort_t* __restrict__ Bw,
                                              float* __restrict__ Cc,
                                              float* __restrict__ sum,
                                              float* __restrict__ ssq,
                                              int M, int K, int Nout) {
  __shared__ __align__(16) ushort_t As[128 * 32];
  __shared__ __align__(16) ushort_t Bs[128 * 32];
  const int tid = threadIdx.x;
  const int m0 = blockIdx.x * 128;
  const int n0 = blockIdx.y * 128;
  const int wave = tid >> 6;
  const int lane = tid & 63;
  const int quad = lane >> 4;
  const int l16 = lane & 15;
  const int wrow = (wave >> 1) * 64;
  const int wcol = (wave & 1) * 64;
  floatx4 acc[4][4];
#pragma unroll
  for (int i = 0; i < 4; i++)
#pragma unroll
    for (int j = 0; j < 4; j++) acc[i][j] = (floatx4){0.f, 0.f, 0.f, 0.f};

  for (int k0 = 0; k0 < K; k0 += 32) {
#pragma unroll
    for (int it = 0; it < 2; it++) {
      int l = tid + it * 256;
      int row = l >> 2, seg = l & 3;
      *(uint4*)&As[row * 32 + seg * 8] = *(const uint4*)&A[(size_t)(m0 + row) * K + k0 + seg * 8];
      *(uint4*)&Bs[row * 32 + seg * 8] = *(const uint4*)&Bw[(size_t)(n0 + row) * K + k0 + seg * 8];
    }
    __syncthreads();
    bf16x8 af[4], bfr[4];
#pragma unroll
    for (int mt = 0; mt < 4; mt++) af[mt] = *(const bf16x8*)&As[(wrow + mt * 16 + l16) * 32 + quad * 8];
#pragma unroll
    for (int nt = 0; nt < 4; nt++) bfr[nt] = *(const bf16x8*)&Bs[(wcol + nt * 16 + l16) * 32 + quad * 8];
#pragma unroll
    for (int mt = 0; mt < 4; mt++)
#pragma unroll
      for (int nt = 0; nt < 4; nt++)
        acc[mt][nt] = __builtin_amdgcn_mfma_f32_16x16x32_bf16(af[mt], bfr[nt], acc[mt][nt], 0, 0, 0);
    __syncthreads();
  }
#pragma unroll
  for (int mt = 0; mt < 4; mt++) {
#pragma unroll
    for (int i = 0; i < 4; i++) {
      int row = m0 + wrow + mt * 16 + quad * 4 + i;
#pragma unroll
      for (int nt = 0; nt < 4; nt++) {
        int col = n0 + wcol + nt * 16 + l16;
        Cc[(size_t)row * Nout + col] = acc[mt][nt][i];
      }
    }
  }
  // fused BN stats: per-column sum/sumsq over this block's 128 rows
#pragma unroll
  for (int nt = 0; nt < 4; nt++) {
    float s = 0.f, s2 = 0.f;
#pragma unroll
    for (int mt = 0; mt < 4; mt++)
#pragma unroll
      for (int i = 0; i < 4; i++) {
        float v = acc[mt][nt][i];
        s += v;
        s2 = fmaf(v, v, s2);
      }
    s += __shfl_xor(s, 16);  s2 += __shfl_xor(s2, 16);
    s += __shfl_xor(s, 32);  s2 += __shfl_xor(s2, 32);
    if (quad == 0) {
      int col = n0 + wcol + nt * 16 + l16;
      atomicAdd(&sum[col], s);
      atomicAdd(&ssq[col], s2);
    }
  }
}

__global__ void k_finalize(const float* __restrict__ sum, const float* __restrict__ ssq,
                           const float* __restrict__ g, const float* __restrict__ be,
                           float* __restrict__ scale, float* __restrict__ shift,
                           float inv_count) {
  int c = threadIdx.x;
  float mean = sum[c] * inv_count;
  float var = ssq[c] * inv_count - mean * mean;
  float sc = rsqrtf(var + 1e-5f) * g[c];
  scale[c] = sc;
  shift[c] = be[c] - mean * sc;
}

// ---------- normalize + relu -> bf16 (layer 1 activations) ----------
__global__ __launch_bounds__(256) void k_norm_relu(const float4* __restrict__ Y,
                                                   const float* __restrict__ scale,
                                                   const float* __restrict__ shift,
                                                   ushort_t* __restrict__ X) {
  int idx = blockIdx.x * 256 + threadIdx.x;  // 4194304 float4s
  float4 y = Y[idx];
  int c = (idx & 63) * 4;
  float v0 = fmaxf(fmaf(y.x, scale[c + 0], shift[c + 0]), 0.f);
  float v1 = fmaxf(fmaf(y.y, scale[c + 1], shift[c + 1]), 0.f);
  float v2 = fmaxf(fmaf(y.z, scale[c + 2], shift[c + 2]), 0.f);
  float v3 = fmaxf(fmaf(y.w, scale[c + 3], shift[c + 3]), 0.f);
  ushort4 o;
  o.x = f2bf(v0); o.y = f2bf(v1); o.z = f2bf(v2); o.w = f2bf(v3);
  *(ushort4*)&X[(size_t)idx * 4] = o;
}

// ---------- final: BN + relu + transpose to [B,128,N] ----------
__global__ __launch_bounds__(256) void k_out(const float* __restrict__ Y2,
                                             const float* __restrict__ scale,
                                             const float* __restrict__ shift,
                                             float* __restrict__ out) {
  __shared__ float t[64 * 129];
  int tid = threadIdx.x;
  int p0 = blockIdx.x * 64;  // 1024 blocks
  int b = p0 >> 13;
  int n0 = p0 & (N_ - 1);
#pragma unroll
  for (int it = 0; it < 32; it++) {
    int idx = it * 256 + tid;
    int r = idx >> 7, c = idx & 127;
    t[r * 129 + c] = Y2[(size_t)(p0 + r) * 128 + c];
  }
  __syncthreads();
#pragma unroll
  for (int it = 0; it < 32; it++) {
    int idx = it * 256 + tid;
    int j = idx & 63, c = idx >> 6;
    float v = fmaxf(fmaf(t[j * 129 + c], scale[c], shift[c]), 0.f);
    out[((size_t)(b * 128 + c)) * N_ + n0 + j] = v;
  }
}

extern "C" void kernel_launch(void* const* d_in, const int* in_sizes, int n_in,
                              void* d_out, int out_size, void* d_ws, size_t ws_size,
                              hipStream_t stream) {
  const float* xyz1    = (const float*)d_in[0];
  const float* xyz2    = (const float*)d_in[1];
  const float* points1 = (const float*)d_in[2];
  const float* points2 = (const float*)d_in[3];
  const float* W0 = (const float*)d_in[4];
  const float* g0 = (const float*)d_in[6];
  const float* be0 = (const float*)d_in[7];
  const float* W1 = (const float*)d_in[8];
  const float* g1 = (const float*)d_in[10];
  const float* be1 = (const float*)d_in[11];
  float* out = (float*)d_out;
  char* ws = (char*)d_ws;

  float* sum0   = (float*)(ws + OFF_STATS);
  float* ssq0   = sum0 + 256;
  float* sum1   = sum0 + 512;
  float* ssq1   = sum0 + 640;
  float* scale0 = sum0 + 768;
  float* shift0 = sum0 + 1024;
  float* scale1 = sum0 + 1280;
  float* shift1 = sum0 + 1408;
  ushort_t* W0b = (ushort_t*)(ws + OFF_W0B);
  ushort_t* W1b = (ushort_t*)(ws + OFF_W1B);
  float4* x2p   = (float4*)(ws + OFF_X2P);
  ushort_t* p2t = (ushort_t*)(ws + OFF_P2T);
  ushort_t* Xc  = (ushort_t*)(ws + OFF_XC);
  ushort_t* X1  = (ushort_t*)(ws + OFF_XC);   // overlays Xc (dead after GEMM1)
  float* Y1     = (float*)(ws + OFF_Y1);
  float* Y2     = (float*)(ws + OFF_Y1);       // overlays Y1 (dead after norm)

  hipMemsetAsync(ws + OFF_STATS, 0, 6144, stream);
  k_prep<<<576, 256, 0, stream>>>(W0, W1, xyz2, W0b, W1b, x2p);
  k_tr_p2<<<dim3(64, 8, 8), dim3(32, 8), 0, stream>>>(points2, p2t);
  k_tr_p1<<<dim3(256, 4, 8), dim3(32, 8), 0, stream>>>(points1, Xc);
  k_knn<<<512, 512, 0, stream>>>(xyz1, x2p, p2t, Xc);
  k_gemm<<<dim3(512, 2), 256, 0, stream>>>(Xc, W0b, Y1, sum0, ssq0, M_, 384, 256);
  k_finalize<<<1, 256, 0, stream>>>(sum0, ssq0, g0, be0, scale0, shift0, 1.f / 65536.f);
  k_norm_relu<<<16384, 256, 0, stream>>>((const float4*)Y1, scale0, shift0, X1);
  k_gemm<<<dim3(512, 1), 256, 0, stream>>>(X1, W1b, Y2, sum1, ssq1, M_, 256, 128);
  k_finalize<<<1, 128, 0, stream>>>(sum1, ssq1, g1, be1, scale1, shift1, 1.f / 65536.f);
  k_out<<<1024, 256, 0, stream>>>(Y2, scale1, shift1, out);
}

// Round 5
// 285.021 us; speedup vs baseline: 2.7302x; 1.1443x over previous
//
#include <hip/hip_runtime.h>

typedef unsigned short ushort_t;
typedef __bf16 bf16x8 __attribute__((ext_vector_type(8)));
typedef float floatx4 __attribute__((ext_vector_type(4)));

#define B_ 8
#define N_ 8192
#define S_ 2048
#define D1_ 128
#define D2_ 256
#define INCH_ 384
#define M_ 65536  // B*N

// ---------- workspace layout (bytes) ----------
constexpr size_t OFF_STATS = 0;          // 6144 B used
constexpr size_t OFF_W0B   = 8192;       // 256*384*2 = 196608
constexpr size_t OFF_W1B   = 204800;     // 128*256*2 = 65536
constexpr size_t OFF_X2P   = 270336;     // 8*2048*16 = 262144 (float4 x,y,z,0.5*|x|^2)
constexpr size_t OFF_P2T   = 532480;     // 8*2048*256*2 = 8388608 bf16
constexpr size_t OFF_XC    = 8921088;    // 65536*384*2 = 50331648 bf16 ; Y2 (33.5 MB f32) overlays after GEMM1
constexpr size_t OFF_Y1    = 59252736;   // 65536*256*4 = 67108864 f32

__device__ __forceinline__ ushort_t f2bf(float f) {
  unsigned int u = __float_as_uint(f);
  unsigned int r = u + 0x7fffu + ((u >> 16) & 1u);
  return (ushort_t)(r >> 16);
}
__device__ __forceinline__ float bf2f(ushort_t h) {
  return __uint_as_float(((unsigned int)h) << 16);
}

// insert (e,s) into sorted top-3 (c0<=c1<=c2); strict < keeps existing on ties
__device__ __forceinline__ void ins3(float e, int s,
                                     float& c0, float& c1, float& c2,
                                     int& i0, int& i1, int& i2) {
  bool l0 = e < c0, l1 = e < c1, l2 = e < c2;
  float nf0 = fminf(e, c0);
  float nf1 = __builtin_amdgcn_fmed3f(e, c0, c1);
  float nf2 = __builtin_amdgcn_fmed3f(e, c1, c2);
  i2 = l1 ? i1 : (l2 ? s : i2);
  i1 = l0 ? i0 : (l1 ? s : i1);
  i0 = l0 ? s : i0;
  c0 = nf0; c1 = nf1; c2 = nf2;
}

// ---------- prep: weights fp32->bf16 + pack xyz2 (one launch) ----------
__global__ __launch_bounds__(256) void k_prep(const float* __restrict__ W0,
                                              const float* __restrict__ W1,
                                              const float* __restrict__ xyz2,
                                              ushort_t* __restrict__ W0b,
                                              ushort_t* __restrict__ W1b,
                                              float4* __restrict__ x2p) {
  int i = blockIdx.x * 256 + threadIdx.x;  // grid 576 = (98304+32768+16384)/256
  if (i < 98304) {
    W0b[i] = f2bf(W0[i]);
  } else if (i < 131072) {
    W1b[i - 98304] = f2bf(W1[i - 98304]);
  } else {
    int idx = i - 131072;  // 16384
    int b = idx >> 11, s = idx & (S_ - 1);
    const float* base = xyz2 + (size_t)b * 3 * S_;
    float x = base[s], y = base[S_ + s], z = base[2 * S_ + s];
    x2p[idx] = make_float4(x, y, z, 0.5f * (x * x + y * y + z * z));
  }
}

// ---------- transpose points2 [B,256,S] -> p2t bf16 [B,S,256] ----------
__global__ void k_tr_p2(const float* __restrict__ P2, ushort_t* __restrict__ p2t) {
  __shared__ float t[32][33];
  int b = blockIdx.z;
  int s0 = blockIdx.x * 32;
  int c0 = blockIdx.y * 32;
  int tx = threadIdx.x, ty = threadIdx.y;  // (32,8)
#pragma unroll
  for (int j = 0; j < 4; j++) {
    int c = c0 + ty + j * 8;
    t[ty + j * 8][tx] = P2[((size_t)b * D2_ + c) * S_ + s0 + tx];
  }
  __syncthreads();
#pragma unroll
  for (int j = 0; j < 4; j++) {
    int s = s0 + ty + j * 8;
    p2t[((size_t)b * S_ + s) * D2_ + c0 + tx] = f2bf(t[tx][ty + j * 8]);
  }
}

// ---------- transpose points1 [B,128,N] -> Xc cols 0..127 (bf16, row stride 384) ----------
__global__ void k_tr_p1(const float* __restrict__ P1, ushort_t* __restrict__ Xc) {
  __shared__ float t[32][33];
  int b = blockIdx.z;
  int n0 = blockIdx.x * 32;
  int c0 = blockIdx.y * 32;
  int tx = threadIdx.x, ty = threadIdx.y;
#pragma unroll
  for (int j = 0; j < 4; j++) {
    int c = c0 + ty + j * 8;
    t[ty + j * 8][tx] = P1[((size_t)b * D1_ + c) * N_ + n0 + tx];
  }
  __syncthreads();
#pragma unroll
  for (int j = 0; j < 4; j++) {
    int n = n0 + ty + j * 8;
    Xc[((size_t)b * N_ + n) * INCH_ + c0 + tx] = f2bf(t[tx][ty + j * 8]);
  }
}

// ---------- kNN + interpolate: 1024 blocks x 512 threads, 64 queries/block ----------
// sub = t&7 (S-chunk of 256 pts; 8 subs of a query live in ONE wave),
// qg = t>>3 in [0,64) -> 1 query/thread-group. shfl_xor merge; no LDS scratch.
__global__ __launch_bounds__(512, 8) void k_knn(const float* __restrict__ xyz1,
                                                const float4* __restrict__ x2p,
                                                const ushort_t* __restrict__ p2t,
                                                ushort_t* __restrict__ Xc) {
  __shared__ float4 xs[S_];          // 32 KB
  __shared__ float wsh[64 * 3];
  __shared__ int   ish[64 * 3];
  int t = threadIdx.x;
  int q0 = blockIdx.x * 64;
  int b = q0 >> 13;
  int n0 = q0 & (N_ - 1);
  for (int l = t; l < S_; l += 512) xs[l] = x2p[(size_t)b * S_ + l];
  int sub = t & 7;
  int qg = t >> 3;
  int n = n0 + qg;
  float qx = xyz1[((size_t)b * 3 + 0) * N_ + n];
  float qy = xyz1[((size_t)b * 3 + 1) * N_ + n];
  float qz = xyz1[((size_t)b * 3 + 2) * N_ + n];
  float c0 = 3e38f, c1 = 3e38f, c2 = 3e38f;
  int i0 = 0, i1 = 0, i2 = 0;
  __syncthreads();
  // e = 0.5*|x2|^2 - dot(x1,x2); true dist d = 2e + |x1|^2 (monotone in e)
  int sbase = sub << 8;
  int stag = (sub * 33) & 255;  // stagger: 8 sub-addresses hit disjoint bank groups
  int s = sbase + stag;
  float4 P = xs[s];
#pragma unroll 4
  for (int i = 0; i < 256; ++i) {
    int ii = (i + 1 + stag) & 255;
    int sn = sbase + ii;
    float4 Pn = xs[sn];  // prefetch next point
    float e = fmaf(-qx, P.x, fmaf(-qy, P.y, fmaf(-qz, P.z, P.w)));
    ins3(e, s, c0, c1, c2, i0, i1, i2);
    P = Pn; s = sn;
  }
  // merge the 8 sub-lists within the wave (lanes differ only in low-3 bits)
#pragma unroll
  for (int d = 1; d < 8; d <<= 1) {
    float e0 = __shfl_xor(c0, d); int s0 = __shfl_xor(i0, d);
    float e1 = __shfl_xor(c1, d); int s1 = __shfl_xor(i1, d);
    float e2 = __shfl_xor(c2, d); int s2 = __shfl_xor(i2, d);
    ins3(e0, s0, c0, c1, c2, i0, i1, i2);
    ins3(e1, s1, c0, c1, c2, i0, i1, i2);
    ins3(e2, s2, c0, c1, c2, i0, i1, i2);
  }
  if (sub == 0) {
    float nrm1 = qx * qx + qy * qy + qz * qz;
    float dd0 = fmaf(2.f, c0, nrm1);
    float dd1 = fmaf(2.f, c1, nrm1);
    float dd2 = fmaf(2.f, c2, nrm1);
    float r0 = 1.f / (dd0 + 1e-8f);
    float r1 = 1.f / (dd1 + 1e-8f);
    float r2 = 1.f / (dd2 + 1e-8f);
    float rs = 1.f / (r0 + r1 + r2);
    wsh[qg * 3 + 0] = r0 * rs; wsh[qg * 3 + 1] = r1 * rs; wsh[qg * 3 + 2] = r2 * rs;
    ish[qg * 3 + 0] = i0; ish[qg * 3 + 1] = i1; ish[qg * 3 + 2] = i2;
  }
  __syncthreads();
  // gather: 8 queries in parallel (8 waves), 64 lanes x 4 channels each
  int lane = t & 63, grp = t >> 6;
  size_t sbase2 = (size_t)b * S_;
#pragma unroll 2
  for (int it = 0; it < 8; ++it) {
    int ql = it * 8 + grp;
    int q = q0 + ql;
    float w0 = wsh[ql * 3 + 0], w1 = wsh[ql * 3 + 1], w2 = wsh[ql * 3 + 2];
    int j0 = ish[ql * 3 + 0], j1 = ish[ql * 3 + 1], j2 = ish[ql * 3 + 2];
    ushort4 a0 = *(const ushort4*)&p2t[(sbase2 + j0) * D2_ + lane * 4];
    ushort4 a1 = *(const ushort4*)&p2t[(sbase2 + j1) * D2_ + lane * 4];
    ushort4 a2 = *(const ushort4*)&p2t[(sbase2 + j2) * D2_ + lane * 4];
    ushort4 o;
    o.x = f2bf(w0 * bf2f(a0.x) + w1 * bf2f(a1.x) + w2 * bf2f(a2.x));
    o.y = f2bf(w0 * bf2f(a0.y) + w1 * bf2f(a1.y) + w2 * bf2f(a2.y));
    o.z = f2bf(w0 * bf2f(a0.z) + w1 * bf2f(a1.z) + w2 * bf2f(a2.z));
    o.w = f2bf(w0 * bf2f(a0.w) + w1 * bf2f(a1.w) + w2 * bf2f(a2.w));
    *(ushort4*)&Xc[(size_t)q * INCH_ + D1_ + lane * 4] = o;
  }
}

// ---------- GEMM1: Y1[M,256] = Xc[M,384] * W0b[256,384]^T, full-width 128x256 tile ----------
__global__ __launch_bounds__(512) void k_gemm1(const ushort_t* __restrict__ A,
                                               const ushort_t* __restrict__ Bw,
                                               float* __restrict__ Cc,
                                               float* __restrict__ sum,
                                               float* __restrict__ ssq) {
  __shared__ __align__(16) ushort_t As[128 * 32];
  __shared__ __align__(16) ushort_t Bs[256 * 32];
  const int tid = threadIdx.x;
  const int m0 = blockIdx.x * 128;
  const int wave = tid >> 6;
  const int lane = tid & 63;
  const int quad = lane >> 4;
  const int l16 = lane & 15;
  const int wrow = (wave >> 2) * 64;   // 2 row-waves
  const int wcol = (wave & 3) * 64;    // 4 col-waves
  floatx4 acc[4][4];
#pragma unroll
  for (int i = 0; i < 4; i++)
#pragma unroll
    for (int j = 0; j < 4; j++) acc[i][j] = (floatx4){0.f, 0.f, 0.f, 0.f};

  for (int k0 = 0; k0 < INCH_; k0 += 32) {
    {
      int row = tid >> 2, seg = tid & 3;
      *(uint4*)&As[row * 32 + seg * 8] = *(const uint4*)&A[(size_t)(m0 + row) * INCH_ + k0 + seg * 8];
    }
#pragma unroll
    for (int it = 0; it < 2; it++) {
      int l = tid + it * 512;
      int row = l >> 2, seg = l & 3;
      *(uint4*)&Bs[row * 32 + seg * 8] = *(const uint4*)&Bw[(size_t)row * INCH_ + k0 + seg * 8];
    }
    __syncthreads();
    bf16x8 af[4], bfr[4];
#pragma unroll
    for (int mt = 0; mt < 4; mt++) af[mt] = *(const bf16x8*)&As[(wrow + mt * 16 + l16) * 32 + quad * 8];
#pragma unroll
    for (int nt = 0; nt < 4; nt++) bfr[nt] = *(const bf16x8*)&Bs[(wcol + nt * 16 + l16) * 32 + quad * 8];
#pragma unroll
    for (int mt = 0; mt < 4; mt++)
#pragma unroll
      for (int nt = 0; nt < 4; nt++)
        acc[mt][nt] = __builtin_amdgcn_mfma_f32_16x16x32_bf16(af[mt], bfr[nt], acc[mt][nt], 0, 0, 0);
    __syncthreads();
  }
#pragma unroll
  for (int mt = 0; mt < 4; mt++) {
#pragma unroll
    for (int i = 0; i < 4; i++) {
      int row = m0 + wrow + mt * 16 + quad * 4 + i;
#pragma unroll
      for (int nt = 0; nt < 4; nt++) {
        int col = wcol + nt * 16 + l16;
        Cc[(size_t)row * 256 + col] = acc[mt][nt][i];
      }
    }
  }
  // fused BN stats: per-column partial sums over this wave's 64 rows
#pragma unroll
  for (int nt = 0; nt < 4; nt++) {
    float s = 0.f, s2 = 0.f;
#pragma unroll
    for (int mt = 0; mt < 4; mt++)
#pragma unroll
      for (int i = 0; i < 4; i++) {
        float v = acc[mt][nt][i];
        s += v;
        s2 = fmaf(v, v, s2);
      }
    s += __shfl_xor(s, 16);  s2 += __shfl_xor(s2, 16);
    s += __shfl_xor(s, 32);  s2 += __shfl_xor(s2, 32);
    if (quad == 0) {
      int col = wcol + nt * 16 + l16;
      atomicAdd(&sum[col], s);
      atomicAdd(&ssq[col], s2);
    }
  }
}

__global__ void k_finalize(const float* __restrict__ sum, const float* __restrict__ ssq,
                           const float* __restrict__ g, const float* __restrict__ be,
                           float* __restrict__ scale, float* __restrict__ shift,
                           float inv_count) {
  int c = threadIdx.x;
  float mean = sum[c] * inv_count;
  float var = ssq[c] * inv_count - mean * mean;
  float sc = rsqrtf(var + 1e-5f) * g[c];
  scale[c] = sc;
  shift[c] = be[c] - mean * sc;
}

// ---------- GEMM2: Y2[M,128] = relu(BN0(Y1))[M,256] * W1b[128,256]^T ----------
// BN0+ReLU+bf16 applied during A-staging (Y1 f32 -> As bf16). Fused BN1 stats.
__global__ __launch_bounds__(256) void k_gemm2(const float* __restrict__ Y1,
                                               const ushort_t* __restrict__ Bw,
                                               const float* __restrict__ scale0,
                                               const float* __restrict__ shift0,
                                               float* __restrict__ Cc,
                                               float* __restrict__ sum,
                                               float* __restrict__ ssq) {
  __shared__ __align__(16) ushort_t As[128 * 32];
  __shared__ __align__(16) ushort_t Bs[128 * 32];
  __shared__ float scs[256], shs[256];
  const int tid = threadIdx.x;
  const int m0 = blockIdx.x * 128;
  const int wave = tid >> 6;
  const int lane = tid & 63;
  const int quad = lane >> 4;
  const int l16 = lane & 15;
  const int wrow = (wave >> 1) * 64;
  const int wcol = (wave & 1) * 64;
  if (tid < 256) { scs[tid] = scale0[tid]; shs[tid] = shift0[tid]; }
  floatx4 acc[4][4];
#pragma unroll
  for (int i = 0; i < 4; i++)
#pragma unroll
    for (int j = 0; j < 4; j++) acc[i][j] = (floatx4){0.f, 0.f, 0.f, 0.f};
  __syncthreads();

  for (int k0 = 0; k0 < 256; k0 += 32) {
    // A: 128 rows x 32 ch of Y1, BN0+relu+bf16 on the fly
#pragma unroll
    for (int it = 0; it < 4; it++) {
      int l = tid + it * 256;
      int row = l >> 3, seg = l & 7;
      float4 y = *(const float4*)&Y1[(size_t)(m0 + row) * 256 + k0 + seg * 4];
      int c = k0 + seg * 4;
      ushort4 o;
      o.x = f2bf(fmaxf(fmaf(y.x, scs[c + 0], shs[c + 0]), 0.f));
      o.y = f2bf(fmaxf(fmaf(y.y, scs[c + 1], shs[c + 1]), 0.f));
      o.z = f2bf(fmaxf(fmaf(y.z, scs[c + 2], shs[c + 2]), 0.f));
      o.w = f2bf(fmaxf(fmaf(y.w, scs[c + 3], shs[c + 3]), 0.f));
      *(ushort4*)&As[row * 32 + seg * 4] = o;
    }
#pragma unroll
    for (int it = 0; it < 2; it++) {
      int l = tid + it * 256;
      int row = l >> 2, seg = l & 3;
      *(uint4*)&Bs[row * 32 + seg * 8] = *(const uint4*)&Bw[(size_t)row * 256 + k0 + seg * 8];
    }
    __syncthreads();
    bf16x8 af[4], bfr[4];
#pragma unroll
    for (int mt = 0; mt < 4; mt++) af[mt] = *(const bf16x8*)&As[(wrow + mt * 16 + l16) * 32 + quad * 8];
#pragma unroll
    for (int nt = 0; nt < 4; nt++) bfr[nt] = *(const bf16x8*)&Bs[(wcol + nt * 16 + l16) * 32 + quad * 8];
#pragma unroll
    for (int mt = 0; mt < 4; mt++)
#pragma unroll
      for (int nt = 0; nt < 4; nt++)
        acc[mt][nt] = __builtin_amdgcn_mfma_f32_16x16x32_bf16(af[mt], bfr[nt], acc[mt][nt], 0, 0, 0);
    __syncthreads();
  }
#pragma unroll
  for (int mt = 0; mt < 4; mt++) {
#pragma unroll
    for (int i = 0; i < 4; i++) {
      int row = m0 + wrow + mt * 16 + quad * 4 + i;
#pragma unroll
      for (int nt = 0; nt < 4; nt++) {
        int col = wcol + nt * 16 + l16;
        Cc[(size_t)row * 128 + col] = acc[mt][nt][i];
      }
    }
  }
#pragma unroll
  for (int nt = 0; nt < 4; nt++) {
    float s = 0.f, s2 = 0.f;
#pragma unroll
    for (int mt = 0; mt < 4; mt++)
#pragma unroll
      for (int i = 0; i < 4; i++) {
        float v = acc[mt][nt][i];
        s += v;
        s2 = fmaf(v, v, s2);
      }
    s += __shfl_xor(s, 16);  s2 += __shfl_xor(s2, 16);
    s += __shfl_xor(s, 32);  s2 += __shfl_xor(s2, 32);
    if (quad == 0) {
      int col = wcol + nt * 16 + l16;
      atomicAdd(&sum[col], s);
      atomicAdd(&ssq[col], s2);
    }
  }
}

// ---------- final: BN + relu + transpose to [B,128,N] ----------
__global__ __launch_bounds__(256) void k_out(const float* __restrict__ Y2,
                                             const float* __restrict__ scale,
                                             const float* __restrict__ shift,
                                             float* __restrict__ out) {
  __shared__ float t[64 * 129];
  int tid = threadIdx.x;
  int p0 = blockIdx.x * 64;  // 1024 blocks
  int b = p0 >> 13;
  int n0 = p0 & (N_ - 1);
#pragma unroll
  for (int it = 0; it < 32; it++) {
    int idx = it * 256 + tid;
    int r = idx >> 7, c = idx & 127;
    t[r * 129 + c] = Y2[(size_t)(p0 + r) * 128 + c];
  }
  __syncthreads();
#pragma unroll
  for (int it = 0; it < 32; it++) {
    int idx = it * 256 + tid;
    int j = idx & 63, c = idx >> 6;
    float v = fmaxf(fmaf(t[j * 129 + c], scale[c], shift[c]), 0.f);
    out[((size_t)(b * 128 + c)) * N_ + n0 + j] = v;
  }
}

extern "C" void kernel_launch(void* const* d_in, const int* in_sizes, int n_in,
                              void* d_out, int out_size, void* d_ws, size_t ws_size,
                              hipStream_t stream) {
  const float* xyz1    = (const float*)d_in[0];
  const float* xyz2    = (const float*)d_in[1];
  const float* points1 = (const float*)d_in[2];
  const float* points2 = (const float*)d_in[3];
  const float* W0 = (const float*)d_in[4];
  const float* g0 = (const float*)d_in[6];
  const float* be0 = (const float*)d_in[7];
  const float* W1 = (const float*)d_in[8];
  const float* g1 = (const float*)d_in[10];
  const float* be1 = (const float*)d_in[11];
  float* out = (float*)d_out;
  char* ws = (char*)d_ws;

  float* sum0   = (float*)(ws + OFF_STATS);
  float* ssq0   = sum0 + 256;
  float* sum1   = sum0 + 512;
  float* ssq1   = sum0 + 640;
  float* scale0 = sum0 + 768;
  float* shift0 = sum0 + 1024;
  float* scale1 = sum0 + 1280;
  float* shift1 = sum0 + 1408;
  ushort_t* W0b = (ushort_t*)(ws + OFF_W0B);
  ushort_t* W1b = (ushort_t*)(ws + OFF_W1B);
  float4* x2p   = (float4*)(ws + OFF_X2P);
  ushort_t* p2t = (ushort_t*)(ws + OFF_P2T);
  ushort_t* Xc  = (ushort_t*)(ws + OFF_XC);
  float* Y1     = (float*)(ws + OFF_Y1);
  float* Y2     = (float*)(ws + OFF_XC);  // overlays Xc (dead after GEMM1)

  hipMemsetAsync(ws + OFF_STATS, 0, 6144, stream);
  k_prep<<<576, 256, 0, stream>>>(W0, W1, xyz2, W0b, W1b, x2p);
  k_tr_p2<<<dim3(64, 8, 8), dim3(32, 8), 0, stream>>>(points2, p2t);
  k_tr_p1<<<dim3(256, 4, 8), dim3(32, 8), 0, stream>>>(points1, Xc);
  k_knn<<<1024, 512, 0, stream>>>(xyz1, x2p, p2t, Xc);
  k_gemm1<<<512, 512, 0, stream>>>(Xc, W0b, Y1, sum0, ssq0);
  k_finalize<<<1, 256, 0, stream>>>(sum0, ssq0, g0, be0, scale0, shift0, 1.f / 65536.f);
  k_gemm2<<<512, 256, 0, stream>>>(Y1, W1b, scale0, shift0, Y2, sum1, ssq1);
  k_finalize<<<1, 128, 0, stream>>>(sum1, ssq1, g1, be1, scale1, shift1, 1.f / 65536.f);
  k_out<<<1024, 256, 0, stream>>>(Y2, scale1, shift1, out);
}

// Round 6
// 284.771 us; speedup vs baseline: 2.7326x; 1.0009x over previous
//
#include <hip/hip_runtime.h>

typedef unsigned short ushort_t;
typedef __bf16 bf16x8 __attribute__((ext_vector_type(8)));
typedef float floatx4 __attribute__((ext_vector_type(4)));

#define B_ 8
#define N_ 8192
#define S_ 2048
#define D1_ 128
#define D2_ 256
#define INCH_ 384
#define M_ 65536  // B*N

// ---------- workspace layout (bytes) ----------
constexpr size_t OFF_STATS = 0;          // 6144 B used
constexpr size_t OFF_W0B   = 8192;       // 256*384*2 = 196608
constexpr size_t OFF_W1B   = 204800;     // 128*256*2 = 65536
constexpr size_t OFF_X2P   = 270336;     // 8*2048*16 = 262144 (float4 x,y,z,0.5*|x|^2)
constexpr size_t OFF_P2T   = 532480;     // 8*2048*256*2 = 8388608 bf16
constexpr size_t OFF_XC    = 8921088;    // 65536*384*2 = 50331648 bf16 ; Y2b (16.8 MB bf16) overlays after GEMM1
constexpr size_t OFF_Y1    = 59252736;   // 65536*256*2 = 33554432 bf16

__device__ __forceinline__ ushort_t f2bf(float f) {
  unsigned int u = __float_as_uint(f);
  unsigned int r = u + 0x7fffu + ((u >> 16) & 1u);
  return (ushort_t)(r >> 16);
}
__device__ __forceinline__ float bf2f(ushort_t h) {
  return __uint_as_float(((unsigned int)h) << 16);
}

// insert (e,s) into sorted top-3 (c0<=c1<=c2); strict < keeps existing on ties
__device__ __forceinline__ void ins3(float e, int s,
                                     float& c0, float& c1, float& c2,
                                     int& i0, int& i1, int& i2) {
  bool l0 = e < c0, l1 = e < c1, l2 = e < c2;
  float nf0 = fminf(e, c0);
  float nf1 = __builtin_amdgcn_fmed3f(e, c0, c1);
  float nf2 = __builtin_amdgcn_fmed3f(e, c1, c2);
  i2 = l1 ? i1 : (l2 ? s : i2);
  i1 = l0 ? i0 : (l1 ? s : i1);
  i0 = l0 ? s : i0;
  c0 = nf0; c1 = nf1; c2 = nf2;
}

// ---------- prep: weights fp32->bf16 + pack xyz2 (one launch) ----------
__global__ __launch_bounds__(256) void k_prep(const float* __restrict__ W0,
                                              const float* __restrict__ W1,
                                              const float* __restrict__ xyz2,
                                              ushort_t* __restrict__ W0b,
                                              ushort_t* __restrict__ W1b,
                                              float4* __restrict__ x2p) {
  int i = blockIdx.x * 256 + threadIdx.x;  // grid 576 = (98304+32768+16384)/256
  if (i < 98304) {
    W0b[i] = f2bf(W0[i]);
  } else if (i < 131072) {
    W1b[i - 98304] = f2bf(W1[i - 98304]);
  } else {
    int idx = i - 131072;  // 16384
    int b = idx >> 11, s = idx & (S_ - 1);
    const float* base = xyz2 + (size_t)b * 3 * S_;
    float x = base[s], y = base[S_ + s], z = base[2 * S_ + s];
    x2p[idx] = make_float4(x, y, z, 0.5f * (x * x + y * y + z * z));
  }
}

// ---------- transpose points2 [B,256,S] -> p2t bf16 [B,S,256] ----------
__global__ void k_tr_p2(const float* __restrict__ P2, ushort_t* __restrict__ p2t) {
  __shared__ float t[32][33];
  int b = blockIdx.z;
  int s0 = blockIdx.x * 32;
  int c0 = blockIdx.y * 32;
  int tx = threadIdx.x, ty = threadIdx.y;  // (32,8)
#pragma unroll
  for (int j = 0; j < 4; j++) {
    int c = c0 + ty + j * 8;
    t[ty + j * 8][tx] = P2[((size_t)b * D2_ + c) * S_ + s0 + tx];
  }
  __syncthreads();
#pragma unroll
  for (int j = 0; j < 4; j++) {
    int s = s0 + ty + j * 8;
    p2t[((size_t)b * S_ + s) * D2_ + c0 + tx] = f2bf(t[tx][ty + j * 8]);
  }
}

// ---------- transpose points1 [B,128,N] -> Xc cols 0..127 (bf16, row stride 384) ----------
__global__ void k_tr_p1(const float* __restrict__ P1, ushort_t* __restrict__ Xc) {
  __shared__ float t[32][33];
  int b = blockIdx.z;
  int n0 = blockIdx.x * 32;
  int c0 = blockIdx.y * 32;
  int tx = threadIdx.x, ty = threadIdx.y;
#pragma unroll
  for (int j = 0; j < 4; j++) {
    int c = c0 + ty + j * 8;
    t[ty + j * 8][tx] = P1[((size_t)b * D1_ + c) * N_ + n0 + tx];
  }
  __syncthreads();
#pragma unroll
  for (int j = 0; j < 4; j++) {
    int n = n0 + ty + j * 8;
    Xc[((size_t)b * N_ + n) * INCH_ + c0 + tx] = f2bf(t[tx][ty + j * 8]);
  }
}

// ---------- kNN + interpolate: 1024 blocks x 512 threads, 64 queries/block ----------
// sub = t&15 (S-chunk of 128 pts; 16 subs of a query live in ONE wave),
// qg = t>>4 in [0,32), 2 queries/thread -> each ds_read amortized over 2 queries.
__global__ __launch_bounds__(512, 8) void k_knn(const float* __restrict__ xyz1,
                                                const float4* __restrict__ x2p,
                                                const ushort_t* __restrict__ p2t,
                                                ushort_t* __restrict__ Xc) {
  __shared__ float4 xs[S_];          // 32 KB
  __shared__ float wsh[64 * 3];
  __shared__ int   ish[64 * 3];
  int t = threadIdx.x;
  int q0 = blockIdx.x * 64;
  int b = q0 >> 13;
  int n0 = q0 & (N_ - 1);
  for (int l = t; l < S_; l += 512) xs[l] = x2p[(size_t)b * S_ + l];
  int sub = t & 15;
  int qg = t >> 4;  // [0,32)
  float qx[2], qy[2], qz[2];
  float c0[2], c1[2], c2[2];
  int i0[2], i1[2], i2[2];
#pragma unroll
  for (int j = 0; j < 2; ++j) {
    int n = n0 + qg * 2 + j;
    qx[j] = xyz1[((size_t)b * 3 + 0) * N_ + n];
    qy[j] = xyz1[((size_t)b * 3 + 1) * N_ + n];
    qz[j] = xyz1[((size_t)b * 3 + 2) * N_ + n];
    c0[j] = 3e38f; c1[j] = 3e38f; c2[j] = 3e38f;
    i0[j] = 0; i1[j] = 0; i2[j] = 0;
  }
  __syncthreads();
  // e = 0.5*|x2|^2 - dot(x1,x2); true dist d = 2e + |x1|^2 (monotone in e)
  int sbase = sub << 7;          // 128 points per sub
  int stag = (sub * 33) & 127;   // (it+sub) mod 8 bank-group spread -> 2-way max (free)
  int s = sbase + stag;
  float4 P = xs[s];
#pragma unroll 4
  for (int i = 0; i < 128; ++i) {
    int ii = (i + 1 + stag) & 127;
    int sn = sbase + ii;
    float4 Pn = xs[sn];  // prefetch next point
#pragma unroll
    for (int j = 0; j < 2; ++j) {
      float e = fmaf(-qx[j], P.x, fmaf(-qy[j], P.y, fmaf(-qz[j], P.z, P.w)));
      ins3(e, s, c0[j], c1[j], c2[j], i0[j], i1[j], i2[j]);
    }
    P = Pn; s = sn;
  }
  // merge the 16 sub-lists within the wave (lanes differ only in low-4 bits)
#pragma unroll
  for (int d = 1; d < 16; d <<= 1) {
#pragma unroll
    for (int j = 0; j < 2; ++j) {
      float e0 = __shfl_xor(c0[j], d); int s0 = __shfl_xor(i0[j], d);
      float e1 = __shfl_xor(c1[j], d); int s1 = __shfl_xor(i1[j], d);
      float e2 = __shfl_xor(c2[j], d); int s2 = __shfl_xor(i2[j], d);
      ins3(e0, s0, c0[j], c1[j], c2[j], i0[j], i1[j], i2[j]);
      ins3(e1, s1, c0[j], c1[j], c2[j], i0[j], i1[j], i2[j]);
      ins3(e2, s2, c0[j], c1[j], c2[j], i0[j], i1[j], i2[j]);
    }
  }
  if (sub == 0) {
#pragma unroll
    for (int j = 0; j < 2; ++j) {
      int ql = qg * 2 + j;
      float nrm1 = qx[j] * qx[j] + qy[j] * qy[j] + qz[j] * qz[j];
      float dd0 = fmaf(2.f, c0[j], nrm1);
      float dd1 = fmaf(2.f, c1[j], nrm1);
      float dd2 = fmaf(2.f, c2[j], nrm1);
      float r0 = 1.f / (dd0 + 1e-8f);
      float r1 = 1.f / (dd1 + 1e-8f);
      float r2 = 1.f / (dd2 + 1e-8f);
      float rs = 1.f / (r0 + r1 + r2);
      wsh[ql * 3 + 0] = r0 * rs; wsh[ql * 3 + 1] = r1 * rs; wsh[ql * 3 + 2] = r2 * rs;
      ish[ql * 3 + 0] = i0[j]; ish[ql * 3 + 1] = i1[j]; ish[ql * 3 + 2] = i2[j];
    }
  }
  __syncthreads();
  // gather: 8 queries in parallel (8 waves), 64 lanes x 4 channels each
  int lane = t & 63, grp = t >> 6;
  size_t sbase2 = (size_t)b * S_;
#pragma unroll 2
  for (int it = 0; it < 8; ++it) {
    int ql = it * 8 + grp;
    int q = q0 + ql;
    float w0 = wsh[ql * 3 + 0], w1 = wsh[ql * 3 + 1], w2 = wsh[ql * 3 + 2];
    int j0 = ish[ql * 3 + 0], j1 = ish[ql * 3 + 1], j2 = ish[ql * 3 + 2];
    ushort4 a0 = *(const ushort4*)&p2t[(sbase2 + j0) * D2_ + lane * 4];
    ushort4 a1 = *(const ushort4*)&p2t[(sbase2 + j1) * D2_ + lane * 4];
    ushort4 a2 = *(const ushort4*)&p2t[(sbase2 + j2) * D2_ + lane * 4];
    ushort4 o;
    o.x = f2bf(w0 * bf2f(a0.x) + w1 * bf2f(a1.x) + w2 * bf2f(a2.x));
    o.y = f2bf(w0 * bf2f(a0.y) + w1 * bf2f(a1.y) + w2 * bf2f(a2.y));
    o.z = f2bf(w0 * bf2f(a0.z) + w1 * bf2f(a1.z) + w2 * bf2f(a2.z));
    o.w = f2bf(w0 * bf2f(a0.w) + w1 * bf2f(a1.w) + w2 * bf2f(a2.w));
    *(ushort4*)&Xc[(size_t)q * INCH_ + D1_ + lane * 4] = o;
  }
}

// ---------- GEMM1: Y1b[M,256](bf16) = Xc[M,384] * W0b[256,384]^T, 128x256 tile ----------
__global__ __launch_bounds__(512) void k_gemm1(const ushort_t* __restrict__ A,
                                               const ushort_t* __restrict__ Bw,
                                               ushort_t* __restrict__ Cc,
                                               float* __restrict__ sum,
                                               float* __restrict__ ssq) {
  __shared__ __align__(16) ushort_t As[128 * 32];
  __shared__ __align__(16) ushort_t Bs[256 * 32];
  const int tid = threadIdx.x;
  const int m0 = blockIdx.x * 128;
  const int wave = tid >> 6;
  const int lane = tid & 63;
  const int quad = lane >> 4;
  const int l16 = lane & 15;
  const int wrow = (wave >> 2) * 64;   // 2 row-waves
  const int wcol = (wave & 3) * 64;    // 4 col-waves
  floatx4 acc[4][4];
#pragma unroll
  for (int i = 0; i < 4; i++)
#pragma unroll
    for (int j = 0; j < 4; j++) acc[i][j] = (floatx4){0.f, 0.f, 0.f, 0.f};

  for (int k0 = 0; k0 < INCH_; k0 += 32) {
    {
      int row = tid >> 2, seg = tid & 3;
      *(uint4*)&As[row * 32 + seg * 8] = *(const uint4*)&A[(size_t)(m0 + row) * INCH_ + k0 + seg * 8];
    }
#pragma unroll
    for (int it = 0; it < 2; it++) {
      int l = tid + it * 512;
      int row = l >> 2, seg = l & 3;
      *(uint4*)&Bs[row * 32 + seg * 8] = *(const uint4*)&Bw[(size_t)row * INCH_ + k0 + seg * 8];
    }
    __syncthreads();
    bf16x8 af[4], bfr[4];
#pragma unroll
    for (int mt = 0; mt < 4; mt++) af[mt] = *(const bf16x8*)&As[(wrow + mt * 16 + l16) * 32 + quad * 8];
#pragma unroll
    for (int nt = 0; nt < 4; nt++) bfr[nt] = *(const bf16x8*)&Bs[(wcol + nt * 16 + l16) * 32 + quad * 8];
#pragma unroll
    for (int mt = 0; mt < 4; mt++)
#pragma unroll
      for (int nt = 0; nt < 4; nt++)
        acc[mt][nt] = __builtin_amdgcn_mfma_f32_16x16x32_bf16(af[mt], bfr[nt], acc[mt][nt], 0, 0, 0);
    __syncthreads();
  }
#pragma unroll
  for (int mt = 0; mt < 4; mt++) {
#pragma unroll
    for (int i = 0; i < 4; i++) {
      int row = m0 + wrow + mt * 16 + quad * 4 + i;
#pragma unroll
      for (int nt = 0; nt < 4; nt++) {
        int col = wcol + nt * 16 + l16;
        Cc[(size_t)row * 256 + col] = f2bf(acc[mt][nt][i]);
      }
    }
  }
  // fused BN stats (f32 acc): per-column partial sums over this wave's 64 rows
#pragma unroll
  for (int nt = 0; nt < 4; nt++) {
    float s = 0.f, s2 = 0.f;
#pragma unroll
    for (int mt = 0; mt < 4; mt++)
#pragma unroll
      for (int i = 0; i < 4; i++) {
        float v = acc[mt][nt][i];
        s += v;
        s2 = fmaf(v, v, s2);
      }
    s += __shfl_xor(s, 16);  s2 += __shfl_xor(s2, 16);
    s += __shfl_xor(s, 32);  s2 += __shfl_xor(s2, 32);
    if (quad == 0) {
      int col = wcol + nt * 16 + l16;
      atomicAdd(&sum[col], s);
      atomicAdd(&ssq[col], s2);
    }
  }
}

__global__ void k_finalize(const float* __restrict__ sum, const float* __restrict__ ssq,
                           const float* __restrict__ g, const float* __restrict__ be,
                           float* __restrict__ scale, float* __restrict__ shift,
                           float inv_count) {
  int c = threadIdx.x;
  float mean = sum[c] * inv_count;
  float var = ssq[c] * inv_count - mean * mean;
  float sc = rsqrtf(var + 1e-5f) * g[c];
  scale[c] = sc;
  shift[c] = be[c] - mean * sc;
}

// ---------- GEMM2: Y2b[M,128](bf16) = relu(BN0(Y1b))[M,256] * W1b[128,256]^T ----------
// BN0+ReLU applied during bf16 A-staging. Fused BN1 stats.
__global__ __launch_bounds__(256) void k_gemm2(const ushort_t* __restrict__ Y1,
                                               const ushort_t* __restrict__ Bw,
                                               const float* __restrict__ scale0,
                                               const float* __restrict__ shift0,
                                               ushort_t* __restrict__ Cc,
                                               float* __restrict__ sum,
                                               float* __restrict__ ssq) {
  __shared__ __align__(16) ushort_t As[128 * 32];
  __shared__ __align__(16) ushort_t Bs[128 * 32];
  __shared__ float scs[256], shs[256];
  const int tid = threadIdx.x;
  const int m0 = blockIdx.x * 128;
  const int wave = tid >> 6;
  const int lane = tid & 63;
  const int quad = lane >> 4;
  const int l16 = lane & 15;
  const int wrow = (wave >> 1) * 64;
  const int wcol = (wave & 1) * 64;
  scs[tid] = scale0[tid]; shs[tid] = shift0[tid];
  floatx4 acc[4][4];
#pragma unroll
  for (int i = 0; i < 4; i++)
#pragma unroll
    for (int j = 0; j < 4; j++) acc[i][j] = (floatx4){0.f, 0.f, 0.f, 0.f};
  __syncthreads();

  for (int k0 = 0; k0 < 256; k0 += 32) {
    // A: 128 rows x 32 ch of bf16 Y1, BN0+relu on the fly
#pragma unroll
    for (int it = 0; it < 2; it++) {
      int l = tid + it * 256;
      int row = l >> 2, seg = l & 3;
      ushort4 y01 = *(const ushort4*)&Y1[(size_t)(m0 + row) * 256 + k0 + seg * 8];
      ushort4 y23 = *(const ushort4*)&Y1[(size_t)(m0 + row) * 256 + k0 + seg * 8 + 4];
      int c = k0 + seg * 8;
      ushort4 o0, o1;
      o0.x = f2bf(fmaxf(fmaf(bf2f(y01.x), scs[c + 0], shs[c + 0]), 0.f));
      o0.y = f2bf(fmaxf(fmaf(bf2f(y01.y), scs[c + 1], shs[c + 1]), 0.f));
      o0.z = f2bf(fmaxf(fmaf(bf2f(y01.z), scs[c + 2], shs[c + 2]), 0.f));
      o0.w = f2bf(fmaxf(fmaf(bf2f(y01.w), scs[c + 3], shs[c + 3]), 0.f));
      o1.x = f2bf(fmaxf(fmaf(bf2f(y23.x), scs[c + 4], shs[c + 4]), 0.f));
      o1.y = f2bf(fmaxf(fmaf(bf2f(y23.y), scs[c + 5], shs[c + 5]), 0.f));
      o1.z = f2bf(fmaxf(fmaf(bf2f(y23.z), scs[c + 6], shs[c + 6]), 0.f));
      o1.w = f2bf(fmaxf(fmaf(bf2f(y23.w), scs[c + 7], shs[c + 7]), 0.f));
      *(ushort4*)&As[row * 32 + seg * 8] = o0;
      *(ushort4*)&As[row * 32 + seg * 8 + 4] = o1;
    }
#pragma unroll
    for (int it = 0; it < 2; it++) {
      int l = tid + it * 256;
      int row = l >> 2, seg = l & 3;
      *(uint4*)&Bs[row * 32 + seg * 8] = *(const uint4*)&Bw[(size_t)row * 256 + k0 + seg * 8];
    }
    __syncthreads();
    bf16x8 af[4], bfr[4];
#pragma unroll
    for (int mt = 0; mt < 4; mt++) af[mt] = *(const bf16x8*)&As[(wrow + mt * 16 + l16) * 32 + quad * 8];
#pragma unroll
    for (int nt = 0; nt < 4; nt++) bfr[nt] = *(const bf16x8*)&Bs[(wcol + nt * 16 + l16) * 32 + quad * 8];
#pragma unroll
    for (int mt = 0; mt < 4; mt++)
#pragma unroll
      for (int nt = 0; nt < 4; nt++)
        acc[mt][nt] = __builtin_amdgcn_mfma_f32_16x16x32_bf16(af[mt], bfr[nt], acc[mt][nt], 0, 0, 0);
    __syncthreads();
  }
#pragma unroll
  for (int mt = 0; mt < 4; mt++) {
#pragma unroll
    for (int i = 0; i < 4; i++) {
      int row = m0 + wrow + mt * 16 + quad * 4 + i;
#pragma unroll
      for (int nt = 0; nt < 4; nt++) {
        int col = wcol + nt * 16 + l16;
        Cc[(size_t)row * 128 + col] = f2bf(acc[mt][nt][i]);
      }
    }
  }
#pragma unroll
  for (int nt = 0; nt < 4; nt++) {
    float s = 0.f, s2 = 0.f;
#pragma unroll
    for (int mt = 0; mt < 4; mt++)
#pragma unroll
      for (int i = 0; i < 4; i++) {
        float v = acc[mt][nt][i];
        s += v;
        s2 = fmaf(v, v, s2);
      }
    s += __shfl_xor(s, 16);  s2 += __shfl_xor(s2, 16);
    s += __shfl_xor(s, 32);  s2 += __shfl_xor(s2, 32);
    if (quad == 0) {
      int col = wcol + nt * 16 + l16;
      atomicAdd(&sum[col], s);
      atomicAdd(&ssq[col], s2);
    }
  }
}

// ---------- final: BN + relu + transpose to [B,128,N] ----------
__global__ __launch_bounds__(256) void k_out(const ushort_t* __restrict__ Y2,
                                             const float* __restrict__ scale,
                                             const float* __restrict__ shift,
                                             float* __restrict__ out) {
  __shared__ float t[64 * 129];
  int tid = threadIdx.x;
  int p0 = blockIdx.x * 64;  // 1024 blocks
  int b = p0 >> 13;
  int n0 = p0 & (N_ - 1);
#pragma unroll
  for (int it = 0; it < 8; it++) {
    int idx = it * 256 + tid;        // [0,2048)
    int r = idx >> 5, c4 = (idx & 31) * 4;
    ushort4 v = *(const ushort4*)&Y2[(size_t)(p0 + r) * 128 + c4];
    t[r * 129 + c4 + 0] = bf2f(v.x);
    t[r * 129 + c4 + 1] = bf2f(v.y);
    t[r * 129 + c4 + 2] = bf2f(v.z);
    t[r * 129 + c4 + 3] = bf2f(v.w);
  }
  __syncthreads();
#pragma unroll
  for (int it = 0; it < 32; it++) {
    int idx = it * 256 + tid;
    int j = idx & 63, c = idx >> 6;
    float v = fmaxf(fmaf(t[j * 129 + c], scale[c], shift[c]), 0.f);
    out[((size_t)(b * 128 + c)) * N_ + n0 + j] = v;
  }
}

extern "C" void kernel_launch(void* const* d_in, const int* in_sizes, int n_in,
                              void* d_out, int out_size, void* d_ws, size_t ws_size,
                              hipStream_t stream) {
  const float* xyz1    = (const float*)d_in[0];
  const float* xyz2    = (const float*)d_in[1];
  const float* points1 = (const float*)d_in[2];
  const float* points2 = (const float*)d_in[3];
  const float* W0 = (const float*)d_in[4];
  const float* g0 = (const float*)d_in[6];
  const float* be0 = (const float*)d_in[7];
  const float* W1 = (const float*)d_in[8];
  const float* g1 = (const float*)d_in[10];
  const float* be1 = (const float*)d_in[11];
  float* out = (float*)d_out;
  char* ws = (char*)d_ws;

  float* sum0   = (float*)(ws + OFF_STATS);
  float* ssq0   = sum0 + 256;
  float* sum1   = sum0 + 512;
  float* ssq1   = sum0 + 640;
  float* scale0 = sum0 + 768;
  float* shift0 = sum0 + 1024;
  float* scale1 = sum0 + 1280;
  float* shift1 = sum0 + 1408;
  ushort_t* W0b = (ushort_t*)(ws + OFF_W0B);
  ushort_t* W1b = (ushort_t*)(ws + OFF_W1B);
  float4* x2p   = (float4*)(ws + OFF_X2P);
  ushort_t* p2t = (ushort_t*)(ws + OFF_P2T);
  ushort_t* Xc  = (ushort_t*)(ws + OFF_XC);
  ushort_t* Y1b = (ushort_t*)(ws + OFF_Y1);
  ushort_t* Y2b = (ushort_t*)(ws + OFF_XC);  // overlays Xc (dead after GEMM1)

  hipMemsetAsync(ws + OFF_STATS, 0, 6144, stream);
  k_prep<<<576, 256, 0, stream>>>(W0, W1, xyz2, W0b, W1b, x2p);
  k_tr_p2<<<dim3(64, 8, 8), dim3(32, 8), 0, stream>>>(points2, p2t);
  k_tr_p1<<<dim3(256, 4, 8), dim3(32, 8), 0, stream>>>(points1, Xc);
  k_knn<<<1024, 512, 0, stream>>>(xyz1, x2p, p2t, Xc);
  k_gemm1<<<512, 512, 0, stream>>>(Xc, W0b, Y1b, sum0, ssq0);
  k_finalize<<<1, 256, 0, stream>>>(sum0, ssq0, g0, be0, scale0, shift0, 1.f / 65536.f);
  k_gemm2<<<512, 256, 0, stream>>>(Y1b, W1b, scale0, shift0, Y2b, sum1, ssq1);
  k_finalize<<<1, 128, 0, stream>>>(sum1, ssq1, g1, be1, scale1, shift1, 1.f / 65536.f);
  k_out<<<1024, 256, 0, stream>>>(Y2b, scale1, shift1, out);
}